// Round 2
// baseline (1791.058 us; speedup 1.0000x reference)
//
#include <hip/hip_runtime.h>
#include <hip/hip_bf16.h>
#include <math.h>

#define N_NODES 10000
#define N_EDGES 320000
#define DIM     176
#define ATT     16
#define SH_HEADS 16
#define THH     4
#define NH      20          // SH_HEADS + TH
#define VD      11          // DIM / SH_HEADS
#define ZDIM    16
#define RDIM    16
#define QK_W    (NH*ATT)    // 320
#define UI_W    (2*DIM)     // 352
#define CH      8           // edge chunk per fused-kernel iteration
#define SIGINV  3.5714285714285716f   // (RDIM-1)/(CUT-RSTART)
#define RSTEP   0.28f                 // (CUT-RSTART)/(RDIM-1)

// ---------------- helpers ----------------

__device__ __forceinline__ void sph16(float x, float y, float z, float* Y) {
    const float s3  = 1.7320508075688772f;
    const float s15 = 3.872983346207417f;
    const float c1  = 0.7905694150420949f;
    const float c2  = 0.6123724356957945f;
    float x2 = x*x, y2 = y*y, z2 = z*z;
    Y[0]  = 1.0f;
    Y[1]  = x;
    Y[2]  = y;
    Y[3]  = z;
    Y[4]  = s3 * x * y;
    Y[5]  = s3 * y * z;
    Y[6]  = 0.5f * (3.0f * z2 - 1.0f);
    Y[7]  = s3 * x * z;
    Y[8]  = 0.5f * s3 * (x2 - y2);
    Y[9]  = c1 * y * (3.0f * x2 - y2);
    Y[10] = s15 * x * y * z;
    Y[11] = c2 * y * (5.0f * z2 - 1.0f);
    Y[12] = 0.5f * z * (5.0f * z2 - 3.0f);
    Y[13] = c2 * x * (5.0f * z2 - 1.0f);
    Y[14] = 0.5f * s15 * z * (x2 - y2);
    Y[15] = c1 * x * (x2 - 3.0f * y2);
}

// ---------------- CSR build ----------------

__global__ __launch_bounds__(256) void k_zero(int* deg) {
    int i = blockIdx.x * 256 + threadIdx.x;
    if (i < N_NODES) deg[i] = 0;
}

__global__ __launch_bounds__(256) void k_deg(const int* edst, int* deg) {
    int e = blockIdx.x * 256 + threadIdx.x;
    if (e < N_EDGES) atomicAdd(&deg[edst[e]], 1);
}

__global__ __launch_bounds__(1024) void k_scan(const int* deg, int* off, int* cursor) {
    __shared__ int sd[1024];
    __shared__ int carry;
    int tid = threadIdx.x;
    if (tid == 0) { off[0] = 0; carry = 0; }
    __syncthreads();
    for (int b0 = 0; b0 < N_NODES; b0 += 1024) {
        int v = (b0 + tid < N_NODES) ? deg[b0 + tid] : 0;
        sd[tid] = v;
        __syncthreads();
        for (int s = 1; s < 1024; s <<= 1) {
            int add = (tid >= s) ? sd[tid - s] : 0;
            __syncthreads();
            sd[tid] += add;
            __syncthreads();
        }
        int incl = sd[tid];
        if (b0 + tid < N_NODES) {
            off[b0 + tid + 1]  = carry + incl;
            cursor[b0 + tid]   = carry + incl - v;
        }
        __syncthreads();
        if (tid == 0) carry += sd[1023];
        __syncthreads();
    }
}

__global__ __launch_bounds__(256) void k_scatter(const int* edst, int* cursor, int* elist) {
    int e = blockIdx.x * 256 + threadIdx.x;
    if (e < N_EDGES) {
        int p = atomicAdd(&cursor[edst[e]], 1);
        elist[p] = e;
    }
}

// gather per-edge scalars into CSR order (coalesced writes)
__global__ __launch_bounds__(256) void k_reorder(const int* elist, const int* esrc,
        const float* dist, const float* swit, const float* vec,
        int* src_c, float* dist_c, float* sc_c, float* vx_c, float* vy_c, float* vz_c) {
    int i = blockIdx.x * 256 + threadIdx.x;
    if (i >= N_EDGES) return;
    int e = elist[i];
    float d = dist[e];
    float inv = 1.0f / d;
    src_c[i]  = esrc[e];
    dist_c[i] = d;
    sc_c[i]   = swit[e] * 0.25f;           // switch / sqrt(ATT)
    vx_c[i]   = vec[(size_t)e*3 + 0] * inv;
    vy_c[i]   = vec[(size_t)e*3 + 1] * inv;
    vz_c[i]   = vec[(size_t)e*3 + 2] * inv;
}

// ---------------- node embedding: xi = LN(z_table[species] @ w_species) ----------------

__global__ __launch_bounds__(256) void k_node_init(const int* species, const float* z_table,
                                                   const float* wsp, float* xi) {
    __shared__ float zs[16 * ZDIM];
    __shared__ float yt[16 * DIM];
    __shared__ float red[256];
    __shared__ float mus[16], rstds[16];
    int base = blockIdx.x * 16;
    int tid  = threadIdx.x;
    { int n = tid >> 4, kk = tid & 15;
      zs[tid] = z_table[species[base + n] * ZDIM + kk]; }
    __syncthreads();
    int c = tid;
    if (c < DIM) {
        float acc[16];
        #pragma unroll
        for (int n = 0; n < 16; n++) acc[n] = 0.0f;
        for (int kk = 0; kk < ZDIM; kk++) {
            float w = wsp[kk * DIM + c];
            #pragma unroll
            for (int n = 0; n < 16; n++) acc[n] += zs[n * ZDIM + kk] * w;
        }
        #pragma unroll
        for (int n = 0; n < 16; n++) yt[n * DIM + c] = acc[n];
    }
    __syncthreads();
    { int n2 = tid >> 4, j = tid & 15;
      float s = 0.0f;
      for (int c2 = j; c2 < DIM; c2 += 16) s += yt[n2 * DIM + c2];
      red[tid] = s; }
    __syncthreads();
    if (tid < 16) { float s = 0; for (int j = 0; j < 16; j++) s += red[tid * 16 + j]; mus[tid] = s / (float)DIM; }
    __syncthreads();
    { int n2 = tid >> 4, j = tid & 15;
      float mu = mus[n2], s = 0.0f;
      for (int c2 = j; c2 < DIM; c2 += 16) { float d = yt[n2 * DIM + c2] - mu; s += d * d; }
      red[tid] = s; }
    __syncthreads();
    if (tid < 16) { float s = 0; for (int j = 0; j < 16; j++) s += red[tid * 16 + j]; rstds[tid] = rsqrtf(s / (float)DIM + 1e-6f); }
    __syncthreads();
    if (c < DIM) {
        #pragma unroll
        for (int n = 0; n < 16; n++)
            xi[(size_t)(base + n) * DIM + c] = (yt[n * DIM + c] - mus[n]) * rstds[n];
    }
}

// ---------------- q/k/v projection (q fp32, k/v bf16) ----------------

__global__ __launch_bounds__(256) void k_qkv(const float* xi, const float* wq, const float* wk,
                                             const float* wv, float* qo, __hip_bfloat16* ko,
                                             __hip_bfloat16* vo) {
    __shared__ float xs[16 * DIM];
    int base = blockIdx.x * 16;
    int tid  = threadIdx.x;
    for (int idx = tid; idx < 16 * DIM; idx += 256) xs[idx] = xi[(size_t)base * DIM + idx];
    __syncthreads();
    for (int c = tid; c < 2 * QK_W + DIM; c += 256) {
        const float* W; int lc, ow;
        if (c < QK_W)            { W = wq; lc = c;            ow = QK_W; }
        else if (c < 2 * QK_W)   { W = wk; lc = c - QK_W;     ow = QK_W; }
        else                     { W = wv; lc = c - 2 * QK_W; ow = DIM;  }
        float acc[16];
        #pragma unroll
        for (int n = 0; n < 16; n++) acc[n] = 0.0f;
        for (int kk = 0; kk < DIM; kk += 4) {
            float w0 = W[(kk + 0) * ow + lc];
            float w1 = W[(kk + 1) * ow + lc];
            float w2 = W[(kk + 2) * ow + lc];
            float w3 = W[(kk + 3) * ow + lc];
            #pragma unroll
            for (int n = 0; n < 16; n++) {
                const float4 xv = *(const float4*)&xs[n * DIM + kk];
                acc[n] += xv.x * w0 + xv.y * w1 + xv.z * w2 + xv.w * w3;
            }
        }
        if (c < QK_W) {
            #pragma unroll
            for (int n = 0; n < 16; n++) qo[(size_t)(base + n) * QK_W + lc] = acc[n];
        } else if (c < 2 * QK_W) {
            #pragma unroll
            for (int n = 0; n < 16; n++) ko[(size_t)(base + n) * QK_W + lc] = __float2bfloat16(acc[n]);
        } else {
            #pragma unroll
            for (int n = 0; n < 16; n++) vo[(size_t)(base + n) * DIM + lc] = __float2bfloat16(acc[n]);
        }
    }
}

// ---------------- fused edge-score + aggregation, layer 0 ----------------
// one block (320 threads) per destination node

__global__ __launch_bounds__(320) void k_fused0(const int* off, const int* src_c,
        const float* dist_c, const float* sc_c,
        const float* vx_c, const float* vy_c, const float* vz_c,
        const float* qf, const __hip_bfloat16* kh, const __hip_bfloat16* vh,
        const float* pw1, const float* pb1, const float* pw2, const float* pb2,
        float* mi, float* Vi) {
    __shared__ float s_w1[16 * 32], s_w2[32 * 16], s_b1[32], s_b2[16];
    __shared__ float s_ur[CH][16];
    __shared__ float s_sj[CH][32];
    __shared__ float s_wd[CH][16];
    __shared__ float s_a[CH][20];
    __shared__ float s_Y[CH][16];
    __shared__ int   s_src[CH];
    __shared__ float s_scale[CH];

    int n   = blockIdx.x;
    int tid = threadIdx.x;
    for (int i = tid; i < 16 * 32; i += 320) s_w1[i] = pw1[i];
    for (int i = tid; i < 32 * 16; i += 320) s_w2[i] = pw2[i];
    if (tid < 32) s_b1[tid] = pb1[tid];
    else if (tid < 48) s_b2[tid - 32] = pb2[tid - 32];

    float qreg = qf[(size_t)n * QK_W + tid];
    float mi_acc = 0.0f, vi_acc = 0.0f;
    int start = off[n], end = off[n + 1];
    __syncthreads();

    for (int i0 = start; i0 < end; i0 += CH) {
        int cnum = end - i0; if (cnum > CH) cnum = CH;
        int c = tid >> 5, j = tid & 31;
        // phase 1: radial, Y, src, scale
        if (tid < 256 && c < cnum) {
            int i = i0 + c;
            if (j < 16) {
                float d  = dist_c[i];
                float cc = 0.8f + (float)j * RSTEP;
                float u  = (d - cc) * SIGINV;
                s_ur[c][j] = __expf(-u * u);
            } else if (j == 16) {
                s_src[c] = src_c[i]; s_scale[c] = sc_c[i];
            } else if (j == 17) {
                float Y[16];
                sph16(vx_c[i], vy_c[i], vz_c[i], Y);
                #pragma unroll
                for (int m = 0; m < 16; m++) s_Y[c][m] = Y[m];
            }
        }
        __syncthreads();
        // phase 2: hidden layer
        if (tid < 256 && c < cnum) {
            float a = s_b1[j];
            #pragma unroll
            for (int i = 0; i < 16; i++) a += s_ur[c][i] * s_w1[i * 32 + j];
            s_sj[c][j] = a / (1.0f + __expf(-a));
        }
        __syncthreads();
        // phase 3: wd
        if (tid < 128) {
            int c2 = tid >> 4, dd = tid & 15;
            if (c2 < cnum) {
                float w = s_b2[dd];
                #pragma unroll
                for (int jj = 0; jj < 32; jj++) w += s_sj[c2][jj] * s_w2[jj * 16 + dd];
                s_wd[c2][dd] = w;
            }
        }
        __syncthreads();
        // phase 4: attention scores (all 320 threads; 16 lanes per head)
        {
            int dd = tid & 15, h = tid >> 4;
            float kv[CH];
            for (int c2 = 0; c2 < cnum; c2++)
                kv[c2] = __bfloat162float(kh[(size_t)s_src[c2] * QK_W + tid]);
            for (int c2 = 0; c2 < cnum; c2++) {
                float p = qreg * kv[c2] * s_wd[c2][dd];
                p += __shfl_xor(p, 8, 16);
                p += __shfl_xor(p, 4, 16);
                p += __shfl_xor(p, 2, 16);
                p += __shfl_xor(p, 1, 16);
                if (dd == 0) s_a[c2][h] = p * s_scale[c2];
            }
        }
        __syncthreads();
        // phase 5: accumulate mi (tid<176) and Vi (tid 176..239)
        if (tid < DIM) {
            int h = tid / VD;
            float vv[CH];
            for (int c2 = 0; c2 < cnum; c2++)
                vv[c2] = __bfloat162float(vh[(size_t)s_src[c2] * DIM + tid]);
            for (int c2 = 0; c2 < cnum; c2++)
                mi_acc += s_a[c2][h] * vv[c2];
        } else if (tid < DIM + 64) {
            int u = tid - DIM, th = u >> 4, sm = u & 15;
            for (int c2 = 0; c2 < cnum; c2++)
                vi_acc += s_a[c2][SH_HEADS + th] * s_Y[c2][sm];
        }
        __syncthreads();
    }
    if (tid < DIM) mi[(size_t)n * DIM + tid] = mi_acc;
    else if (tid < DIM + 64) Vi[(size_t)n * 64 + (tid - DIM)] = vi_acc;
}

// ---------------- fused edge-score + aggregation, layer 1 ----------------

__global__ __launch_bounds__(320) void k_fused1(const int* off, const int* src_c,
        const float* dist_c, const float* sc_c,
        const float* vx_c, const float* vy_c, const float* vz_c,
        const float* qf, const __hip_bfloat16* kh, const __hip_bfloat16* vh,
        const float* Vi,
        const float* pw1, const float* pb1, const float* pw2, const float* pb2,
        float* mi) {
    __shared__ float s_w1[32 * 32], s_w2[32 * 16], s_b1[32], s_b2[16];
    __shared__ float s_ur[CH][32];
    __shared__ float s_sj[CH][32];
    __shared__ float s_wd[CH][16];
    __shared__ float s_a[CH][20];
    __shared__ float s_Y[CH][16];
    __shared__ float s_Vs[CH][64];
    __shared__ float s_Vd[64];
    __shared__ int   s_src[CH];
    __shared__ float s_scale[CH];

    int n   = blockIdx.x;
    int tid = threadIdx.x;
    for (int i = tid; i < 32 * 32; i += 320) s_w1[i] = pw1[i];
    for (int i = tid; i < 32 * 16; i += 320) s_w2[i] = pw2[i];
    if (tid < 32) s_b1[tid] = pb1[tid];
    else if (tid < 48) s_b2[tid - 32] = pb2[tid - 32];
    if (tid < 64) s_Vd[tid] = Vi[(size_t)n * 64 + tid];

    float qreg = qf[(size_t)n * QK_W + tid];
    float mi_acc = 0.0f;
    int start = off[n], end = off[n + 1];
    __syncthreads();

    for (int i0 = start; i0 < end; i0 += CH) {
        int cnum = end - i0; if (cnum > CH) cnum = CH;
        int c = tid >> 5, j = tid & 31;
        // phase 1a: radial, Y, Vi[src] stage, src, scale
        if (tid < 256 && c < cnum) {
            int i = i0 + c;
            int sv = src_c[i];               // same addr across the 32 lanes -> broadcast
            s_Vs[c][j]      = Vi[(size_t)sv * 64 + j];
            s_Vs[c][j + 32] = Vi[(size_t)sv * 64 + j + 32];
            if (j < 16) {
                float d  = dist_c[i];
                float cc = 0.8f + (float)j * RSTEP;
                float u  = (d - cc) * SIGINV;
                s_ur[c][j] = __expf(-u * u);
            } else if (j == 16) {
                s_src[c] = sv; s_scale[c] = sc_c[i];
            } else if (j == 17) {
                float Y[16];
                sph16(vx_c[i], vy_c[i], vz_c[i], Y);
                #pragma unroll
                for (int m = 0; m < 16; m++) s_Y[c][m] = Y[m];
            }
        }
        __syncthreads();
        // phase 1b: us features -> ur[16..31]  (j = l*4+th)
        if (tid < 256 && c < cnum && j < 16) {
            int l = j >> 2, th = j & 3;
            float sign = (l & 1) ? -1.0f : 1.0f;
            int m0 = l * l, m1 = (l + 1) * (l + 1);
            float s = 0.0f;
            for (int m = m0; m < m1; m++)
                s += (s_Vd[th * 16 + m] + sign * s_Vs[c][th * 16 + m]) * s_Y[c][m];
            s_ur[c][16 + j] = s;
        }
        __syncthreads();
        // phase 2: hidden layer (32-dim input)
        if (tid < 256 && c < cnum) {
            float a = s_b1[j];
            #pragma unroll
            for (int i = 0; i < 32; i++) a += s_ur[c][i] * s_w1[i * 32 + j];
            s_sj[c][j] = a / (1.0f + __expf(-a));
        }
        __syncthreads();
        // phase 3: wd
        if (tid < 128) {
            int c2 = tid >> 4, dd = tid & 15;
            if (c2 < cnum) {
                float w = s_b2[dd];
                #pragma unroll
                for (int jj = 0; jj < 32; jj++) w += s_sj[c2][jj] * s_w2[jj * 16 + dd];
                s_wd[c2][dd] = w;
            }
        }
        __syncthreads();
        // phase 4: attention scores
        {
            int dd = tid & 15, h = tid >> 4;
            float kv[CH];
            for (int c2 = 0; c2 < cnum; c2++)
                kv[c2] = __bfloat162float(kh[(size_t)s_src[c2] * QK_W + tid]);
            for (int c2 = 0; c2 < cnum; c2++) {
                float p = qreg * kv[c2] * s_wd[c2][dd];
                p += __shfl_xor(p, 8, 16);
                p += __shfl_xor(p, 4, 16);
                p += __shfl_xor(p, 2, 16);
                p += __shfl_xor(p, 1, 16);
                if (dd == 0) s_a[c2][h] = p * s_scale[c2];
            }
        }
        __syncthreads();
        // phase 5: accumulate mi only (layer-1 Vi is never used downstream)
        if (tid < DIM) {
            int h = tid / VD;
            float vv[CH];
            for (int c2 = 0; c2 < cnum; c2++)
                vv[c2] = __bfloat162float(vh[(size_t)s_src[c2] * DIM + tid]);
            for (int c2 = 0; c2 < cnum; c2++)
                mi_acc += s_a[c2][h] * vv[c2];
        }
        __syncthreads();
    }
    if (tid < DIM) mi[(size_t)n * DIM + tid] = mi_acc;
}

// ---------------- update: xo = LN(xi + [xi,mi] @ uw + ub) ----------------

__global__ __launch_bounds__(256) void k_update(const float* xi, const float* mi,
        const float* uw, const float* ub, float* xo) {
    __shared__ float us_[16 * UI_W];
    __shared__ float yt[16 * DIM];
    __shared__ float red[256];
    __shared__ float mus[16], rstds[16];
    int base = blockIdx.x * 16;
    int tid  = threadIdx.x;
    for (int idx = tid; idx < 16 * UI_W; idx += 256) {
        int n = idx / UI_W, kk = idx - n * UI_W;
        us_[idx] = (kk < DIM) ? xi[(size_t)(base + n) * DIM + kk]
                              : mi[(size_t)(base + n) * DIM + (kk - DIM)];
    }
    __syncthreads();
    int c = tid;
    if (c < DIM) {
        float acc[16];
        #pragma unroll
        for (int n = 0; n < 16; n++) acc[n] = 0.0f;
        for (int kk = 0; kk < UI_W; kk += 4) {
            float w0 = uw[(kk + 0) * DIM + c];
            float w1 = uw[(kk + 1) * DIM + c];
            float w2 = uw[(kk + 2) * DIM + c];
            float w3 = uw[(kk + 3) * DIM + c];
            #pragma unroll
            for (int n = 0; n < 16; n++) {
                const float4 xv = *(const float4*)&us_[n * UI_W + kk];
                acc[n] += xv.x * w0 + xv.y * w1 + xv.z * w2 + xv.w * w3;
            }
        }
        float bb = ub[c];
        #pragma unroll
        for (int n = 0; n < 16; n++) yt[n * DIM + c] = us_[n * UI_W + c] + acc[n] + bb;
    }
    __syncthreads();
    { int n2 = tid >> 4, j = tid & 15;
      float s = 0.0f;
      for (int c2 = j; c2 < DIM; c2 += 16) s += yt[n2 * DIM + c2];
      red[tid] = s; }
    __syncthreads();
    if (tid < 16) { float s = 0; for (int j = 0; j < 16; j++) s += red[tid * 16 + j]; mus[tid] = s / (float)DIM; }
    __syncthreads();
    { int n2 = tid >> 4, j = tid & 15;
      float mu = mus[n2], s = 0.0f;
      for (int c2 = j; c2 < DIM; c2 += 16) { float d = yt[n2 * DIM + c2] - mu; s += d * d; }
      red[tid] = s; }
    __syncthreads();
    if (tid < 16) { float s = 0; for (int j = 0; j < 16; j++) s += red[tid * 16 + j]; rstds[tid] = rsqrtf(s / (float)DIM + 1e-6f); }
    __syncthreads();
    if (c < DIM) {
        #pragma unroll
        for (int n = 0; n < 16; n++)
            xo[(size_t)(base + n) * DIM + c] = (yt[n * DIM + c] - mus[n]) * rstds[n];
    }
}

// ---------------- launch ----------------

extern "C" void kernel_launch(void* const* d_in, const int* in_sizes, int n_in,
                              void* d_out, int out_size, void* d_ws, size_t ws_size,
                              hipStream_t stream) {
    const int*   species = (const int*)  d_in[0];
    const float* dist    = (const float*)d_in[1];
    const float* swit    = (const float*)d_in[2];
    const int*   esrc    = (const int*)  d_in[3];
    const int*   edst    = (const int*)  d_in[4];
    const float* vec     = (const float*)d_in[5];
    const float* z_table = (const float*)d_in[6];
    const float* wsp     = (const float*)d_in[7];
    const float* pw1_0 = (const float*)d_in[8],  *pb1_0 = (const float*)d_in[9];
    const float* pw2_0 = (const float*)d_in[10], *pb2_0 = (const float*)d_in[11];
    const float* wq0 = (const float*)d_in[12], *wk0 = (const float*)d_in[13];
    const float* wv0 = (const float*)d_in[14], *uw0 = (const float*)d_in[15];
    const float* ub0 = (const float*)d_in[16];
    const float* pw1_1 = (const float*)d_in[17], *pb1_1 = (const float*)d_in[18];
    const float* pw2_1 = (const float*)d_in[19], *pb2_1 = (const float*)d_in[20];
    const float* wq1 = (const float*)d_in[21], *wk1 = (const float*)d_in[22];
    const float* wv1 = (const float*)d_in[23], *uw1 = (const float*)d_in[24];
    const float* ub1 = (const float*)d_in[25];
    float* out = (float*)d_out;

    char* p = (char*)d_ws;
    auto alloc = [&](size_t bytes) -> char* {
        char* r = p;
        p += (bytes + 255) & ~(size_t)255;
        return r;
    };
    int* deg    = (int*)alloc((size_t)N_NODES * 4);
    int* off    = (int*)alloc((size_t)(N_NODES + 1) * 4);
    int* cursor = (int*)alloc((size_t)N_NODES * 4);
    int* elist  = (int*)alloc((size_t)N_EDGES * 4);
    int*   src_c  = (int*)  alloc((size_t)N_EDGES * 4);
    float* dist_c = (float*)alloc((size_t)N_EDGES * 4);
    float* sc_c   = (float*)alloc((size_t)N_EDGES * 4);
    float* vx_c   = (float*)alloc((size_t)N_EDGES * 4);
    float* vy_c   = (float*)alloc((size_t)N_EDGES * 4);
    float* vz_c   = (float*)alloc((size_t)N_EDGES * 4);
    float* xiA  = (float*)alloc((size_t)N_NODES * DIM * 4);
    float* xiB  = (float*)alloc((size_t)N_NODES * DIM * 4);
    float* qf   = (float*)alloc((size_t)N_NODES * QK_W * 4);
    __hip_bfloat16* kh = (__hip_bfloat16*)alloc((size_t)N_NODES * QK_W * 2);
    __hip_bfloat16* vh = (__hip_bfloat16*)alloc((size_t)N_NODES * DIM * 2);
    float* Vi   = (float*)alloc((size_t)N_NODES * 64 * 4);
    float* mi   = (float*)alloc((size_t)N_NODES * DIM * 4);

    const int NB_N  = (N_NODES + 255) / 256;
    const int NB_E  = (N_EDGES + 255) / 256;
    const int NB_T  = N_NODES / 16;   // 625

    k_zero<<<NB_N, 256, 0, stream>>>(deg);
    k_deg<<<NB_E, 256, 0, stream>>>(edst, deg);
    k_scan<<<1, 1024, 0, stream>>>(deg, off, cursor);
    k_scatter<<<NB_E, 256, 0, stream>>>(edst, cursor, elist);
    k_reorder<<<NB_E, 256, 0, stream>>>(elist, esrc, dist, swit, vec,
                                        src_c, dist_c, sc_c, vx_c, vy_c, vz_c);

    k_node_init<<<NB_T, 256, 0, stream>>>(species, z_table, wsp, xiA);

    // layer 0
    k_qkv<<<NB_T, 256, 0, stream>>>(xiA, wq0, wk0, wv0, qf, kh, vh);
    k_fused0<<<N_NODES, 320, 0, stream>>>(off, src_c, dist_c, sc_c, vx_c, vy_c, vz_c,
                                          qf, kh, vh, pw1_0, pb1_0, pw2_0, pb2_0, mi, Vi);
    k_update<<<NB_T, 256, 0, stream>>>(xiA, mi, uw0, ub0, xiB);

    // layer 1
    k_qkv<<<NB_T, 256, 0, stream>>>(xiB, wq1, wk1, wv1, qf, kh, vh);
    k_fused1<<<N_NODES, 320, 0, stream>>>(off, src_c, dist_c, sc_c, vx_c, vy_c, vz_c,
                                          qf, kh, vh, Vi, pw1_1, pb1_1, pw2_1, pb2_1, mi);
    k_update<<<NB_T, 256, 0, stream>>>(xiB, mi, uw1, ub1, out);
}

// Round 3
// 902.930 us; speedup vs baseline: 1.9836x; 1.9836x over previous
//
#include <hip/hip_runtime.h>
#include <hip/hip_bf16.h>
#include <math.h>

#define N_NODES 10000
#define N_EDGES 320000
#define DIM     176
#define ATT     16
#define SH_HEADS 16
#define THH     4
#define NH      20          // SH_HEADS + TH
#define VD      11          // DIM / SH_HEADS
#define ZDIM    16
#define RDIM    16
#define QK_W    (NH*ATT)    // 320
#define UI_W    (2*DIM)     // 352
#define SIGINV  3.5714285714285716f   // (RDIM-1)/(CUT-RSTART)
#define RSTEP   0.28f                 // (CUT-RSTART)/(RDIM-1)

typedef unsigned short ushort_t;

// ---------------- helpers ----------------

__device__ __forceinline__ void sph16(float x, float y, float z, float* Y) {
    const float s3  = 1.7320508075688772f;
    const float s15 = 3.872983346207417f;
    const float c1  = 0.7905694150420949f;
    const float c2  = 0.6123724356957945f;
    float x2 = x*x, y2 = y*y, z2 = z*z;
    Y[0]  = 1.0f;
    Y[1]  = x;
    Y[2]  = y;
    Y[3]  = z;
    Y[4]  = s3 * x * y;
    Y[5]  = s3 * y * z;
    Y[6]  = 0.5f * (3.0f * z2 - 1.0f);
    Y[7]  = s3 * x * z;
    Y[8]  = 0.5f * s3 * (x2 - y2);
    Y[9]  = c1 * y * (3.0f * x2 - y2);
    Y[10] = s15 * x * y * z;
    Y[11] = c2 * y * (5.0f * z2 - 1.0f);
    Y[12] = 0.5f * z * (5.0f * z2 - 3.0f);
    Y[13] = c2 * x * (5.0f * z2 - 1.0f);
    Y[14] = 0.5f * s15 * z * (x2 - y2);
    Y[15] = c1 * x * (x2 - 3.0f * y2);
}

__device__ __forceinline__ float sel16(const float* Y, int i) {
    float a0 = (i & 1) ? Y[1]  : Y[0];
    float a1 = (i & 1) ? Y[3]  : Y[2];
    float a2 = (i & 1) ? Y[5]  : Y[4];
    float a3 = (i & 1) ? Y[7]  : Y[6];
    float a4 = (i & 1) ? Y[9]  : Y[8];
    float a5 = (i & 1) ? Y[11] : Y[10];
    float a6 = (i & 1) ? Y[13] : Y[12];
    float a7 = (i & 1) ? Y[15] : Y[14];
    float b0 = (i & 2) ? a1 : a0;
    float b1 = (i & 2) ? a3 : a2;
    float b2 = (i & 2) ? a5 : a4;
    float b3 = (i & 2) ? a7 : a6;
    float c0 = (i & 4) ? b1 : b0;
    float c1 = (i & 4) ? b3 : b2;
    return (i & 8) ? c1 : c0;
}

__device__ __forceinline__ void unpack8(const uint4 u, float* f) {
    f[0] = __uint_as_float(u.x << 16);
    f[1] = __uint_as_float(u.x & 0xffff0000u);
    f[2] = __uint_as_float(u.y << 16);
    f[3] = __uint_as_float(u.y & 0xffff0000u);
    f[4] = __uint_as_float(u.z << 16);
    f[5] = __uint_as_float(u.z & 0xffff0000u);
    f[6] = __uint_as_float(u.w << 16);
    f[7] = __uint_as_float(u.w & 0xffff0000u);
}

// ---------------- CSR build ----------------

__global__ __launch_bounds__(256) void k_zero(int* deg) {
    int i = blockIdx.x * 256 + threadIdx.x;
    if (i < N_NODES) deg[i] = 0;
}

__global__ __launch_bounds__(256) void k_deg(const int* edst, int* deg) {
    int e = blockIdx.x * 256 + threadIdx.x;
    if (e < N_EDGES) atomicAdd(&deg[edst[e]], 1);
}

__global__ __launch_bounds__(1024) void k_scan(const int* deg, int* off, int* cursor) {
    __shared__ int sd[1024];
    __shared__ int carry;
    int tid = threadIdx.x;
    if (tid == 0) { off[0] = 0; carry = 0; }
    __syncthreads();
    for (int b0 = 0; b0 < N_NODES; b0 += 1024) {
        int v = (b0 + tid < N_NODES) ? deg[b0 + tid] : 0;
        sd[tid] = v;
        __syncthreads();
        for (int s = 1; s < 1024; s <<= 1) {
            int add = (tid >= s) ? sd[tid - s] : 0;
            __syncthreads();
            sd[tid] += add;
            __syncthreads();
        }
        int incl = sd[tid];
        if (b0 + tid < N_NODES) {
            off[b0 + tid + 1]  = carry + incl;
            cursor[b0 + tid]   = carry + incl - v;
        }
        __syncthreads();
        if (tid == 0) carry += sd[1023];
        __syncthreads();
    }
}

__global__ __launch_bounds__(256) void k_scatter(const int* edst, int* cursor, int* elist) {
    int e = blockIdx.x * 256 + threadIdx.x;
    if (e < N_EDGES) {
        int p = atomicAdd(&cursor[edst[e]], 1);
        elist[p] = e;
    }
}

// gather per-edge data into CSR order (coalesced writes)
__global__ __launch_bounds__(256) void k_reorder(const int* elist, const int* esrc, const int* edst,
        const float* dist, const float* swit, const float* vec,
        int* src_c, int* dst_c, float* dist_c, float* sc_c,
        float* vx_c, float* vy_c, float* vz_c) {
    int i = blockIdx.x * 256 + threadIdx.x;
    if (i >= N_EDGES) return;
    int e = elist[i];
    float d = dist[e];
    float inv = 1.0f / d;
    src_c[i]  = esrc[e];
    dst_c[i]  = edst[e];
    dist_c[i] = d;
    sc_c[i]   = swit[e] * 0.25f;           // switch / sqrt(ATT)
    vx_c[i]   = vec[(size_t)e*3 + 0] * inv;
    vy_c[i]   = vec[(size_t)e*3 + 1] * inv;
    vz_c[i]   = vec[(size_t)e*3 + 2] * inv;
}

// ---------------- node embedding ----------------

__global__ __launch_bounds__(256) void k_node_init(const int* species, const float* z_table,
                                                   const float* wsp, float* xi) {
    __shared__ float zs[16 * ZDIM];
    __shared__ float yt[16 * DIM];
    __shared__ float red[256];
    __shared__ float mus[16], rstds[16];
    int base = blockIdx.x * 16;
    int tid  = threadIdx.x;
    { int n = tid >> 4, kk = tid & 15;
      zs[tid] = z_table[species[base + n] * ZDIM + kk]; }
    __syncthreads();
    int c = tid;
    if (c < DIM) {
        float acc[16];
        #pragma unroll
        for (int n = 0; n < 16; n++) acc[n] = 0.0f;
        for (int kk = 0; kk < ZDIM; kk++) {
            float w = wsp[kk * DIM + c];
            #pragma unroll
            for (int n = 0; n < 16; n++) acc[n] += zs[n * ZDIM + kk] * w;
        }
        #pragma unroll
        for (int n = 0; n < 16; n++) yt[n * DIM + c] = acc[n];
    }
    __syncthreads();
    { int n2 = tid >> 4, j = tid & 15;
      float s = 0.0f;
      for (int c2 = j; c2 < DIM; c2 += 16) s += yt[n2 * DIM + c2];
      red[tid] = s; }
    __syncthreads();
    if (tid < 16) { float s = 0; for (int j = 0; j < 16; j++) s += red[tid * 16 + j]; mus[tid] = s / (float)DIM; }
    __syncthreads();
    { int n2 = tid >> 4, j = tid & 15;
      float mu = mus[n2], s = 0.0f;
      for (int c2 = j; c2 < DIM; c2 += 16) { float d = yt[n2 * DIM + c2] - mu; s += d * d; }
      red[tid] = s; }
    __syncthreads();
    if (tid < 16) { float s = 0; for (int j = 0; j < 16; j++) s += red[tid * 16 + j]; rstds[tid] = rsqrtf(s / (float)DIM + 1e-6f); }
    __syncthreads();
    if (c < DIM) {
        #pragma unroll
        for (int n = 0; n < 16; n++)
            xi[(size_t)(base + n) * DIM + c] = (yt[n * DIM + c] - mus[n]) * rstds[n];
    }
}

// ---------------- q/k/v projection (all bf16 outputs) ----------------

__global__ __launch_bounds__(256) void k_qkv(const float* xi, const float* wq, const float* wk,
                                             const float* wv, ushort_t* qo, ushort_t* ko,
                                             ushort_t* vo) {
    __shared__ float xs[16 * DIM];
    int base = blockIdx.x * 16;
    int tid  = threadIdx.x;
    for (int idx = tid; idx < 16 * DIM; idx += 256) xs[idx] = xi[(size_t)base * DIM + idx];
    __syncthreads();
    for (int c = tid; c < 2 * QK_W + DIM; c += 256) {
        const float* W; int lc, ow;
        if (c < QK_W)            { W = wq; lc = c;            ow = QK_W; }
        else if (c < 2 * QK_W)   { W = wk; lc = c - QK_W;     ow = QK_W; }
        else                     { W = wv; lc = c - 2 * QK_W; ow = DIM;  }
        float acc[16];
        #pragma unroll
        for (int n = 0; n < 16; n++) acc[n] = 0.0f;
        for (int kk = 0; kk < DIM; kk += 4) {
            float w0 = W[(kk + 0) * ow + lc];
            float w1 = W[(kk + 1) * ow + lc];
            float w2 = W[(kk + 2) * ow + lc];
            float w3 = W[(kk + 3) * ow + lc];
            #pragma unroll
            for (int n = 0; n < 16; n++) {
                const float4 xv = *(const float4*)&xs[n * DIM + kk];
                acc[n] += xv.x * w0 + xv.y * w1 + xv.z * w2 + xv.w * w3;
            }
        }
        ushort_t* O = (c < QK_W) ? qo : (c < 2 * QK_W) ? ko : vo;
        #pragma unroll
        for (int n = 0; n < 16; n++) {
            __hip_bfloat16 b = __float2bfloat16(acc[n]);
            O[(size_t)(base + n) * ow + lc] = *(ushort_t*)&b;
        }
    }
}

// ---------------- edge kernel, layer 0 (one thread per CSR edge) ----------------

__global__ __launch_bounds__(256) void k_edge0(const int* src_c, const int* dst_c,
        const float* dist_c, const float* sc_c,
        const ushort_t* qh, const ushort_t* kh,
        const float* pw1, const float* pb1, const float* pw2, const float* pb2,
        float* aij) {
    __shared__ float s_w1[RDIM * 32], s_w2[32 * 16], s_b1[32], s_b2[16];
    int tid = threadIdx.x;
    for (int i = tid; i < RDIM * 32; i += 256) s_w1[i] = pw1[i];
    for (int i = tid; i < 32 * 16; i += 256) s_w2[i] = pw2[i];
    if (tid < 32) s_b1[tid] = pb1[tid];
    if (tid < 16) s_b2[tid] = pb2[tid];
    __syncthreads();
    int i = blockIdx.x * 256 + tid;
    if (i >= N_EDGES) return;
    float d = dist_c[i], sc = sc_c[i];
    int s = src_c[i], t_ = dst_c[i];
    float ur[RDIM];
    #pragma unroll
    for (int r = 0; r < 16; r++) {
        float cc = 0.8f + (float)r * RSTEP;
        float u  = (d - cc) * SIGINV;
        ur[r] = __expf(-u * u);
    }
    float wd[16];
    #pragma unroll
    for (int dd = 0; dd < 16; dd++) wd[dd] = s_b2[dd];
    for (int j = 0; j < 32; j++) {
        float a = s_b1[j];
        #pragma unroll
        for (int r = 0; r < 16; r++) a += ur[r] * s_w1[r * 32 + j];
        float sj = a / (1.0f + __expf(-a));
        #pragma unroll
        for (int dd = 0; dd < 16; dd++) wd[dd] += sj * s_w2[j * 16 + dd];
    }
    const uint4* q4 = (const uint4*)(qh + (size_t)t_ * QK_W);
    const uint4* k4 = (const uint4*)(kh + (size_t)s  * QK_W);
    for (int h = 0; h < NH; h++) {
        float qa[8], qb[8], ka[8], kb[8];
        unpack8(q4[2*h],   qa); unpack8(q4[2*h+1], qb);
        unpack8(k4[2*h],   ka); unpack8(k4[2*h+1], kb);
        float acc = 0.0f;
        #pragma unroll
        for (int dd = 0; dd < 8; dd++) acc += qa[dd] * ka[dd] * wd[dd];
        #pragma unroll
        for (int dd = 0; dd < 8; dd++) acc += qb[dd] * kb[dd] * wd[8 + dd];
        aij[(size_t)i * NH + h] = acc * sc;
    }
}

// ---------------- edge kernel, layer 1 ----------------

__global__ __launch_bounds__(256) void k_edge1(const int* src_c, const int* dst_c,
        const float* dist_c, const float* sc_c,
        const float* vx_c, const float* vy_c, const float* vz_c,
        const ushort_t* qh, const ushort_t* kh, const ushort_t* Vih,
        const float* pw1, const float* pb1, const float* pw2, const float* pb2,
        float* aij) {
    __shared__ float s_w1[32 * 32], s_w2[32 * 16], s_b1[32], s_b2[16];
    int tid = threadIdx.x;
    for (int i = tid; i < 32 * 32; i += 256) s_w1[i] = pw1[i];
    for (int i = tid; i < 32 * 16; i += 256) s_w2[i] = pw2[i];
    if (tid < 32) s_b1[tid] = pb1[tid];
    if (tid < 16) s_b2[tid] = pb2[tid];
    __syncthreads();
    int i = blockIdx.x * 256 + tid;
    if (i >= N_EDGES) return;
    float d = dist_c[i], sc = sc_c[i];
    int s = src_c[i], t_ = dst_c[i];
    float ur[32];
    #pragma unroll
    for (int r = 0; r < 16; r++) {
        float cc = 0.8f + (float)r * RSTEP;
        float u  = (d - cc) * SIGINV;
        ur[r] = __expf(-u * u);
    }
    float Y[16];
    sph16(vx_c[i], vy_c[i], vz_c[i], Y);
    const uint4* vd4 = (const uint4*)(Vih + (size_t)t_ * 64);
    const uint4* vs4 = (const uint4*)(Vih + (size_t)s  * 64);
    #pragma unroll
    for (int th = 0; th < THH; th++) {
        float fd[16], fs[16];
        unpack8(vd4[2*th],   fd);     unpack8(vd4[2*th+1], fd+8);
        unpack8(vs4[2*th],   fs);     unpack8(vs4[2*th+1], fs+8);
        float us0 = (fd[0] + fs[0]) * Y[0];
        float us1 = 0.0f, us2 = 0.0f, us3 = 0.0f;
        #pragma unroll
        for (int m = 1; m < 4; m++)  us1 += (fd[m] - fs[m]) * Y[m];
        #pragma unroll
        for (int m = 4; m < 9; m++)  us2 += (fd[m] + fs[m]) * Y[m];
        #pragma unroll
        for (int m = 9; m < 16; m++) us3 += (fd[m] - fs[m]) * Y[m];
        ur[16 + 0 * 4 + th] = us0;
        ur[16 + 1 * 4 + th] = us1;
        ur[16 + 2 * 4 + th] = us2;
        ur[16 + 3 * 4 + th] = us3;
    }
    float wd[16];
    #pragma unroll
    for (int dd = 0; dd < 16; dd++) wd[dd] = s_b2[dd];
    for (int j = 0; j < 32; j++) {
        float a = s_b1[j];
        #pragma unroll
        for (int r = 0; r < 32; r++) a += ur[r] * s_w1[r * 32 + j];
        float sj = a / (1.0f + __expf(-a));
        #pragma unroll
        for (int dd = 0; dd < 16; dd++) wd[dd] += sj * s_w2[j * 16 + dd];
    }
    const uint4* q4 = (const uint4*)(qh + (size_t)t_ * QK_W);
    const uint4* k4 = (const uint4*)(kh + (size_t)s  * QK_W);
    for (int h = 0; h < NH; h++) {
        float qa[8], qb[8], ka[8], kb[8];
        unpack8(q4[2*h],   qa); unpack8(q4[2*h+1], qb);
        unpack8(k4[2*h],   ka); unpack8(k4[2*h+1], kb);
        float acc = 0.0f;
        #pragma unroll
        for (int dd = 0; dd < 8; dd++) acc += qa[dd] * ka[dd] * wd[dd];
        #pragma unroll
        for (int dd = 0; dd < 8; dd++) acc += qb[dd] * kb[dd] * wd[8 + dd];
        aij[(size_t)i * NH + h] = acc * sc;
    }
}

// ---------------- aggregation, layer 0: mi and Vi (bf16 out for Vi) ----------------

__global__ __launch_bounds__(256) void k_agg0(const int* off, const int* src_c,
        const float* vx_c, const float* vy_c, const float* vz_c,
        const float* aij, const ushort_t* vh,
        float* mi, ushort_t* Vih) {
    int n = blockIdx.x;
    int tid = threadIdx.x;
    int start = off[n], end = off[n + 1];
    float acc = 0.0f;
    if (tid < DIM) {
        int h = tid / VD;
        for (int i = start; i < end; i++) {
            int s = src_c[i];
            float vv = __uint_as_float(((unsigned)vh[(size_t)s * DIM + tid]) << 16);
            acc += aij[(size_t)i * NH + h] * vv;
        }
        mi[(size_t)n * DIM + tid] = acc;
    } else if (tid < DIM + 64) {
        int u = tid - DIM;
        int th = u >> 4, sm = u & 15;
        for (int i = start; i < end; i++) {
            float Y[16];
            sph16(vx_c[i], vy_c[i], vz_c[i], Y);
            acc += aij[(size_t)i * NH + SH_HEADS + th] * sel16(Y, sm);
        }
        __hip_bfloat16 b = __float2bfloat16(acc);
        Vih[(size_t)n * 64 + u] = *(ushort_t*)&b;
    }
}

// ---------------- aggregation, layer 1: mi only ----------------

__global__ __launch_bounds__(256) void k_agg1(const int* off, const int* src_c,
        const float* aij, const ushort_t* vh, float* mi) {
    int n = blockIdx.x;
    int tid = threadIdx.x;
    if (tid >= DIM) return;
    int start = off[n], end = off[n + 1];
    int h = tid / VD;
    float acc = 0.0f;
    for (int i = start; i < end; i++) {
        int s = src_c[i];
        float vv = __uint_as_float(((unsigned)vh[(size_t)s * DIM + tid]) << 16);
        acc += aij[(size_t)i * NH + h] * vv;
    }
    mi[(size_t)n * DIM + tid] = acc;
}

// ---------------- update: xo = LN(xi + [xi,mi] @ uw + ub) ----------------

__global__ __launch_bounds__(256) void k_update(const float* xi, const float* mi,
        const float* uw, const float* ub, float* xo) {
    __shared__ float us_[16 * UI_W];
    __shared__ float yt[16 * DIM];
    __shared__ float red[256];
    __shared__ float mus[16], rstds[16];
    int base = blockIdx.x * 16;
    int tid  = threadIdx.x;
    for (int idx = tid; idx < 16 * UI_W; idx += 256) {
        int n = idx / UI_W, kk = idx - n * UI_W;
        us_[idx] = (kk < DIM) ? xi[(size_t)(base + n) * DIM + kk]
                              : mi[(size_t)(base + n) * DIM + (kk - DIM)];
    }
    __syncthreads();
    int c = tid;
    if (c < DIM) {
        float acc[16];
        #pragma unroll
        for (int n = 0; n < 16; n++) acc[n] = 0.0f;
        for (int kk = 0; kk < UI_W; kk += 4) {
            float w0 = uw[(kk + 0) * DIM + c];
            float w1 = uw[(kk + 1) * DIM + c];
            float w2 = uw[(kk + 2) * DIM + c];
            float w3 = uw[(kk + 3) * DIM + c];
            #pragma unroll
            for (int n = 0; n < 16; n++) {
                const float4 xv = *(const float4*)&us_[n * UI_W + kk];
                acc[n] += xv.x * w0 + xv.y * w1 + xv.z * w2 + xv.w * w3;
            }
        }
        float bb = ub[c];
        #pragma unroll
        for (int n = 0; n < 16; n++) yt[n * DIM + c] = us_[n * UI_W + c] + acc[n] + bb;
    }
    __syncthreads();
    { int n2 = tid >> 4, j = tid & 15;
      float s = 0.0f;
      for (int c2 = j; c2 < DIM; c2 += 16) s += yt[n2 * DIM + c2];
      red[tid] = s; }
    __syncthreads();
    if (tid < 16) { float s = 0; for (int j = 0; j < 16; j++) s += red[tid * 16 + j]; mus[tid] = s / (float)DIM; }
    __syncthreads();
    { int n2 = tid >> 4, j = tid & 15;
      float mu = mus[n2], s = 0.0f;
      for (int c2 = j; c2 < DIM; c2 += 16) { float d = yt[n2 * DIM + c2] - mu; s += d * d; }
      red[tid] = s; }
    __syncthreads();
    if (tid < 16) { float s = 0; for (int j = 0; j < 16; j++) s += red[tid * 16 + j]; rstds[tid] = rsqrtf(s / (float)DIM + 1e-6f); }
    __syncthreads();
    if (c < DIM) {
        #pragma unroll
        for (int n = 0; n < 16; n++)
            xo[(size_t)(base + n) * DIM + c] = (yt[n * DIM + c] - mus[n]) * rstds[n];
    }
}

// ---------------- launch ----------------

extern "C" void kernel_launch(void* const* d_in, const int* in_sizes, int n_in,
                              void* d_out, int out_size, void* d_ws, size_t ws_size,
                              hipStream_t stream) {
    const int*   species = (const int*)  d_in[0];
    const float* dist    = (const float*)d_in[1];
    const float* swit    = (const float*)d_in[2];
    const int*   esrc    = (const int*)  d_in[3];
    const int*   edst    = (const int*)  d_in[4];
    const float* vec     = (const float*)d_in[5];
    const float* z_table = (const float*)d_in[6];
    const float* wsp     = (const float*)d_in[7];
    const float* pw1_0 = (const float*)d_in[8],  *pb1_0 = (const float*)d_in[9];
    const float* pw2_0 = (const float*)d_in[10], *pb2_0 = (const float*)d_in[11];
    const float* wq0 = (const float*)d_in[12], *wk0 = (const float*)d_in[13];
    const float* wv0 = (const float*)d_in[14], *uw0 = (const float*)d_in[15];
    const float* ub0 = (const float*)d_in[16];
    const float* pw1_1 = (const float*)d_in[17], *pb1_1 = (const float*)d_in[18];
    const float* pw2_1 = (const float*)d_in[19], *pb2_1 = (const float*)d_in[20];
    const float* wq1 = (const float*)d_in[21], *wk1 = (const float*)d_in[22];
    const float* wv1 = (const float*)d_in[23], *uw1 = (const float*)d_in[24];
    const float* ub1 = (const float*)d_in[25];
    float* out = (float*)d_out;

    char* p = (char*)d_ws;
    auto alloc = [&](size_t bytes) -> char* {
        char* r = p;
        p += (bytes + 255) & ~(size_t)255;
        return r;
    };
    int* deg    = (int*)alloc((size_t)N_NODES * 4);
    int* off    = (int*)alloc((size_t)(N_NODES + 1) * 4);
    int* cursor = (int*)alloc((size_t)N_NODES * 4);
    int* elist  = (int*)alloc((size_t)N_EDGES * 4);
    int*   src_c  = (int*)  alloc((size_t)N_EDGES * 4);
    int*   dst_c  = (int*)  alloc((size_t)N_EDGES * 4);
    float* dist_c = (float*)alloc((size_t)N_EDGES * 4);
    float* sc_c   = (float*)alloc((size_t)N_EDGES * 4);
    float* vx_c   = (float*)alloc((size_t)N_EDGES * 4);
    float* vy_c   = (float*)alloc((size_t)N_EDGES * 4);
    float* vz_c   = (float*)alloc((size_t)N_EDGES * 4);
    float* xiA  = (float*)alloc((size_t)N_NODES * DIM * 4);
    float* xiB  = (float*)alloc((size_t)N_NODES * DIM * 4);
    ushort_t* qh = (ushort_t*)alloc((size_t)N_NODES * QK_W * 2);
    ushort_t* kh = (ushort_t*)alloc((size_t)N_NODES * QK_W * 2);
    ushort_t* vh = (ushort_t*)alloc((size_t)N_NODES * DIM * 2);
    ushort_t* Vih = (ushort_t*)alloc((size_t)N_NODES * 64 * 2);
    float* aij  = (float*)alloc((size_t)N_EDGES * NH * 4);
    float* mi   = (float*)alloc((size_t)N_NODES * DIM * 4);

    const int NB_N  = (N_NODES + 255) / 256;
    const int NB_E  = (N_EDGES + 255) / 256;
    const int NB_T  = N_NODES / 16;   // 625

    k_zero<<<NB_N, 256, 0, stream>>>(deg);
    k_deg<<<NB_E, 256, 0, stream>>>(edst, deg);
    k_scan<<<1, 1024, 0, stream>>>(deg, off, cursor);
    k_scatter<<<NB_E, 256, 0, stream>>>(edst, cursor, elist);
    k_reorder<<<NB_E, 256, 0, stream>>>(elist, esrc, edst, dist, swit, vec,
                                        src_c, dst_c, dist_c, sc_c, vx_c, vy_c, vz_c);

    k_node_init<<<NB_T, 256, 0, stream>>>(species, z_table, wsp, xiA);

    // layer 0
    k_qkv<<<NB_T, 256, 0, stream>>>(xiA, wq0, wk0, wv0, qh, kh, vh);
    k_edge0<<<NB_E, 256, 0, stream>>>(src_c, dst_c, dist_c, sc_c, qh, kh,
                                      pw1_0, pb1_0, pw2_0, pb2_0, aij);
    k_agg0<<<N_NODES, 256, 0, stream>>>(off, src_c, vx_c, vy_c, vz_c, aij, vh, mi, Vih);
    k_update<<<NB_T, 256, 0, stream>>>(xiA, mi, uw0, ub0, xiB);

    // layer 1
    k_qkv<<<NB_T, 256, 0, stream>>>(xiB, wq1, wk1, wv1, qh, kh, vh);
    k_edge1<<<NB_E, 256, 0, stream>>>(src_c, dst_c, dist_c, sc_c, vx_c, vy_c, vz_c,
                                      qh, kh, Vih, pw1_1, pb1_1, pw2_1, pb2_1, aij);
    k_agg1<<<N_NODES, 256, 0, stream>>>(off, src_c, aij, vh, mi);
    k_update<<<NB_T, 256, 0, stream>>>(xiB, mi, uw1, ub1, out);
}

// Round 4
// 653.415 us; speedup vs baseline: 2.7411x; 1.3819x over previous
//
#include <hip/hip_runtime.h>
#include <hip/hip_bf16.h>
#include <math.h>

#define N_NODES 10000
#define N_PAD   10048       // 157 * 64
#define N_EDGES 320000
#define DIM     176
#define ATT     16
#define SH_HEADS 16
#define THH     4
#define NH      20          // SH_HEADS + TH
#define VD      11          // DIM / SH_HEADS
#define ZDIM    16
#define RDIM    16
#define QK_W    (NH*ATT)    // 320
#define QKV_W   816         // 320+320+176
#define UI_W    (2*DIM)     // 352
#define KQ      192         // padded K for qkv gemm
#define SIGINV  3.5714285714285716f   // (RDIM-1)/(CUT-RSTART)
#define RSTEP   0.28f                 // (CUT-RSTART)/(RDIM-1)

typedef unsigned short ushort_t;
typedef __attribute__((ext_vector_type(8))) short bf16x8;
typedef __attribute__((ext_vector_type(4))) float f32x4;

// ---------------- helpers ----------------

__device__ __forceinline__ ushort_t f2bf(float f) {
    __hip_bfloat16 b = __float2bfloat16(f);
    return *(ushort_t*)&b;
}

__device__ __forceinline__ void sph16(float x, float y, float z, float* Y) {
    const float s3  = 1.7320508075688772f;
    const float s15 = 3.872983346207417f;
    const float c1  = 0.7905694150420949f;
    const float c2  = 0.6123724356957945f;
    float x2 = x*x, y2 = y*y, z2 = z*z;
    Y[0]  = 1.0f;
    Y[1]  = x;
    Y[2]  = y;
    Y[3]  = z;
    Y[4]  = s3 * x * y;
    Y[5]  = s3 * y * z;
    Y[6]  = 0.5f * (3.0f * z2 - 1.0f);
    Y[7]  = s3 * x * z;
    Y[8]  = 0.5f * s3 * (x2 - y2);
    Y[9]  = c1 * y * (3.0f * x2 - y2);
    Y[10] = s15 * x * y * z;
    Y[11] = c2 * y * (5.0f * z2 - 1.0f);
    Y[12] = 0.5f * z * (5.0f * z2 - 3.0f);
    Y[13] = c2 * x * (5.0f * z2 - 1.0f);
    Y[14] = 0.5f * s15 * z * (x2 - y2);
    Y[15] = c1 * x * (x2 - 3.0f * y2);
}

__device__ __forceinline__ float sel16(const float* Y, int i) {
    float a0 = (i & 1) ? Y[1]  : Y[0];
    float a1 = (i & 1) ? Y[3]  : Y[2];
    float a2 = (i & 1) ? Y[5]  : Y[4];
    float a3 = (i & 1) ? Y[7]  : Y[6];
    float a4 = (i & 1) ? Y[9]  : Y[8];
    float a5 = (i & 1) ? Y[11] : Y[10];
    float a6 = (i & 1) ? Y[13] : Y[12];
    float a7 = (i & 1) ? Y[15] : Y[14];
    float b0 = (i & 2) ? a1 : a0;
    float b1 = (i & 2) ? a3 : a2;
    float b2 = (i & 2) ? a5 : a4;
    float b3 = (i & 2) ? a7 : a6;
    float c0 = (i & 4) ? b1 : b0;
    float c1 = (i & 4) ? b3 : b2;
    return (i & 8) ? c1 : c0;
}

__device__ __forceinline__ void unpack8(const uint4 u, float* f) {
    f[0] = __uint_as_float(u.x << 16);
    f[1] = __uint_as_float(u.x & 0xffff0000u);
    f[2] = __uint_as_float(u.y << 16);
    f[3] = __uint_as_float(u.y & 0xffff0000u);
    f[4] = __uint_as_float(u.z << 16);
    f[5] = __uint_as_float(u.z & 0xffff0000u);
    f[6] = __uint_as_float(u.w << 16);
    f[7] = __uint_as_float(u.w & 0xffff0000u);
}

// ---------------- CSR build ----------------

__global__ __launch_bounds__(256) void k_zero(int* deg) {
    int i = blockIdx.x * 256 + threadIdx.x;
    if (i < N_NODES) deg[i] = 0;
}

__global__ __launch_bounds__(256) void k_deg(const int* edst, int* deg) {
    int e = blockIdx.x * 256 + threadIdx.x;
    if (e < N_EDGES) atomicAdd(&deg[edst[e]], 1);
}

__global__ __launch_bounds__(1024) void k_scan(const int* deg, int* off, int* cursor) {
    __shared__ int sd[1024];
    __shared__ int carry;
    int tid = threadIdx.x;
    if (tid == 0) { off[0] = 0; carry = 0; }
    __syncthreads();
    for (int b0 = 0; b0 < N_NODES; b0 += 1024) {
        int v = (b0 + tid < N_NODES) ? deg[b0 + tid] : 0;
        sd[tid] = v;
        __syncthreads();
        for (int s = 1; s < 1024; s <<= 1) {
            int add = (tid >= s) ? sd[tid - s] : 0;
            __syncthreads();
            sd[tid] += add;
            __syncthreads();
        }
        int incl = sd[tid];
        if (b0 + tid < N_NODES) {
            off[b0 + tid + 1]  = carry + incl;
            cursor[b0 + tid]   = carry + incl - v;
        }
        __syncthreads();
        if (tid == 0) carry += sd[1023];
        __syncthreads();
    }
}

__global__ __launch_bounds__(256) void k_scatter(const int* edst, int* cursor, int* elist) {
    int e = blockIdx.x * 256 + threadIdx.x;
    if (e < N_EDGES) {
        int p = atomicAdd(&cursor[edst[e]], 1);
        elist[p] = e;
    }
}

__global__ __launch_bounds__(256) void k_reorder(const int* elist, const int* esrc, const int* edst,
        const float* dist, const float* swit, const float* vec,
        int* src_c, int* dst_c, float* dist_c, float* sc_c,
        float* vx_c, float* vy_c, float* vz_c) {
    int i = blockIdx.x * 256 + threadIdx.x;
    if (i >= N_EDGES) return;
    int e = elist[i];
    float d = dist[e];
    float inv = 1.0f / d;
    src_c[i]  = esrc[e];
    dst_c[i]  = edst[e];
    dist_c[i] = d;
    sc_c[i]   = swit[e] * 0.25f;           // switch / sqrt(ATT)
    vx_c[i]   = vec[(size_t)e*3 + 0] * inv;
    vy_c[i]   = vec[(size_t)e*3 + 1] * inv;
    vz_c[i]   = vec[(size_t)e*3 + 2] * inv;
}

// ---------------- weight prep (fp32 -> transposed bf16, padded) ----------------

// Wtq[832][192]: Wtq[n][k] = [wq|wk|wv](k, n), zero-padded
__global__ __launch_bounds__(256) void k_prep_qkv(const float* wq, const float* wk,
                                                  const float* wv, ushort_t* Wtq) {
    int id = blockIdx.x * 256 + threadIdx.x;
    if (id >= 192 * 832) return;
    int k = id / 832, n = id - (id / 832) * 832;
    float v = 0.0f;
    if (k < DIM && n < QKV_W)
        v = (n < 320) ? wq[k * 320 + n] : (n < 640) ? wk[k * 320 + (n - 320)]
                                                    : wv[k * DIM + (n - 640)];
    Wtq[(size_t)n * KQ + k] = f2bf(v);
}

// Wtu[192][352]: Wtu[n][k] = uw(k, n), zero-padded rows n>=176
__global__ __launch_bounds__(256) void k_prep_upd(const float* uw, ushort_t* Wtu) {
    int id = blockIdx.x * 256 + threadIdx.x;
    if (id >= 352 * 192) return;
    int k = id / 192, n = id - (id / 192) * 192;
    float v = (n < DIM) ? uw[k * DIM + n] : 0.0f;
    Wtu[(size_t)n * UI_W + k] = f2bf(v);
}

// ---------------- MFMA GEMM: C[M x N] = A[M x K] @ Bt[N x K]^T ----------------
// A bf16 row-major (stride sA, rows padded to tile), Bt bf16 [N x K] (stride sB),
// C fp32 or bf16. Block 256 = 4 waves; tile 64x64; K in chunks of 32.

template<int KCHUNKS, bool BF16OUT>
__global__ __launch_bounds__(256) void k_gemm(const ushort_t* __restrict__ A, int sA,
                                              const ushort_t* __restrict__ Bt, int sB,
                                              void* __restrict__ Cv, int sC, int M, int N) {
    __shared__ ushort_t As[64 * 40];   // +8 pad breaks b128 bank aliasing
    __shared__ ushort_t Bs[64 * 40];
    int tid  = threadIdx.x;
    int m0   = blockIdx.y * 64, n0 = blockIdx.x * 64;
    int w    = tid >> 6, lane = tid & 63, quad = lane >> 4, c16 = lane & 15;
    int arow = tid >> 2, aseg = tid & 3;
    f32x4 acc[4] = {};
    for (int kc = 0; kc < KCHUNKS; kc++) {
        int k0 = kc * 32;
        *(uint4*)&As[arow * 40 + aseg * 8] =
            *(const uint4*)&A[(size_t)(m0 + arow) * sA + k0 + aseg * 8];
        *(uint4*)&Bs[arow * 40 + aseg * 8] =
            *(const uint4*)&Bt[(size_t)(n0 + arow) * sB + k0 + aseg * 8];
        __syncthreads();
        bf16x8 a = *(const bf16x8*)&As[(w * 16 + c16) * 40 + quad * 8];
        #pragma unroll
        for (int t = 0; t < 4; t++) {
            bf16x8 b = *(const bf16x8*)&Bs[(t * 16 + c16) * 40 + quad * 8];
            acc[t] = __builtin_amdgcn_mfma_f32_16x16x32_bf16(a, b, acc[t], 0, 0, 0);
        }
        __syncthreads();
    }
    #pragma unroll
    for (int t = 0; t < 4; t++) {
        #pragma unroll
        for (int r = 0; r < 4; r++) {
            int row = m0 + w * 16 + quad * 4 + r;
            int col = n0 + t * 16 + c16;
            if (row < M && col < N) {
                if (BF16OUT)
                    ((ushort_t*)Cv)[(size_t)row * sC + col] = f2bf(acc[t][r]);
                else
                    ((float*)Cv)[(size_t)row * sC + col] = acc[t][r];
            }
        }
    }
}

// ---------------- node embedding (writes fp32 xi + bf16 xib + bf16 cxm[:,0:176]) ----

__global__ __launch_bounds__(256) void k_node_init(const int* species, const float* z_table,
                                                   const float* wsp, float* xi,
                                                   ushort_t* xib, ushort_t* cxm) {
    __shared__ float zs[16 * ZDIM];
    __shared__ float yt[16 * DIM];
    __shared__ float red[256];
    __shared__ float mus[16], rstds[16];
    int base = blockIdx.x * 16;
    int tid  = threadIdx.x;
    { int n = tid >> 4, kk = tid & 15;
      zs[tid] = z_table[species[base + n] * ZDIM + kk]; }
    __syncthreads();
    int c = tid;
    if (c < DIM) {
        float acc[16];
        #pragma unroll
        for (int n = 0; n < 16; n++) acc[n] = 0.0f;
        for (int kk = 0; kk < ZDIM; kk++) {
            float w = wsp[kk * DIM + c];
            #pragma unroll
            for (int n = 0; n < 16; n++) acc[n] += zs[n * ZDIM + kk] * w;
        }
        #pragma unroll
        for (int n = 0; n < 16; n++) yt[n * DIM + c] = acc[n];
    }
    __syncthreads();
    { int n2 = tid >> 4, j = tid & 15;
      float s = 0.0f;
      for (int c2 = j; c2 < DIM; c2 += 16) s += yt[n2 * DIM + c2];
      red[tid] = s; }
    __syncthreads();
    if (tid < 16) { float s = 0; for (int j = 0; j < 16; j++) s += red[tid * 16 + j]; mus[tid] = s / (float)DIM; }
    __syncthreads();
    { int n2 = tid >> 4, j = tid & 15;
      float mu = mus[n2], s = 0.0f;
      for (int c2 = j; c2 < DIM; c2 += 16) { float d = yt[n2 * DIM + c2] - mu; s += d * d; }
      red[tid] = s; }
    __syncthreads();
    if (tid < 16) { float s = 0; for (int j = 0; j < 16; j++) s += red[tid * 16 + j]; rstds[tid] = rsqrtf(s / (float)DIM + 1e-6f); }
    __syncthreads();
    if (c < DIM) {
        #pragma unroll
        for (int n = 0; n < 16; n++) {
            float val = (yt[n * DIM + c] - mus[n]) * rstds[n];
            xi[(size_t)(base + n) * DIM + c] = val;
            ushort_t bv = f2bf(val);
            xib[(size_t)(base + n) * KQ + c]   = bv;
            cxm[(size_t)(base + n) * UI_W + c] = bv;
        }
    } else if (c < KQ) {
        #pragma unroll
        for (int n = 0; n < 16; n++) xib[(size_t)(base + n) * KQ + c] = 0;
    }
}

// ---------------- edge kernel, layer 0 ----------------

__global__ __launch_bounds__(256) void k_edge0(const int* src_c, const int* dst_c,
        const float* dist_c, const float* sc_c,
        const ushort_t* qkvh,
        const float* pw1, const float* pb1, const float* pw2, const float* pb2,
        float* aij) {
    __shared__ float s_w1[RDIM * 32], s_w2[32 * 16], s_b1[32], s_b2[16];
    int tid = threadIdx.x;
    for (int i = tid; i < RDIM * 32; i += 256) s_w1[i] = pw1[i];
    for (int i = tid; i < 32 * 16; i += 256) s_w2[i] = pw2[i];
    if (tid < 32) s_b1[tid] = pb1[tid];
    if (tid < 16) s_b2[tid] = pb2[tid];
    __syncthreads();
    int i = blockIdx.x * 256 + tid;
    if (i >= N_EDGES) return;
    float d = dist_c[i], sc = sc_c[i];
    int s = src_c[i], t_ = dst_c[i];
    float ur[RDIM];
    #pragma unroll
    for (int r = 0; r < 16; r++) {
        float cc = 0.8f + (float)r * RSTEP;
        float u  = (d - cc) * SIGINV;
        ur[r] = __expf(-u * u);
    }
    float wd[16];
    #pragma unroll
    for (int dd = 0; dd < 16; dd++) wd[dd] = s_b2[dd];
    for (int j = 0; j < 32; j++) {
        float a = s_b1[j];
        #pragma unroll
        for (int r = 0; r < 16; r++) a += ur[r] * s_w1[r * 32 + j];
        float sj = a / (1.0f + __expf(-a));
        #pragma unroll
        for (int dd = 0; dd < 16; dd++) wd[dd] += sj * s_w2[j * 16 + dd];
    }
    const uint4* q4 = (const uint4*)(qkvh + (size_t)t_ * QKV_W);
    const uint4* k4 = (const uint4*)(qkvh + (size_t)s  * QKV_W + QK_W);
    for (int h = 0; h < NH; h++) {
        float qa[8], qb[8], ka[8], kb[8];
        unpack8(q4[2*h],   qa); unpack8(q4[2*h+1], qb);
        unpack8(k4[2*h],   ka); unpack8(k4[2*h+1], kb);
        float acc = 0.0f;
        #pragma unroll
        for (int dd = 0; dd < 8; dd++) acc += qa[dd] * ka[dd] * wd[dd];
        #pragma unroll
        for (int dd = 0; dd < 8; dd++) acc += qb[dd] * kb[dd] * wd[8 + dd];
        aij[(size_t)i * NH + h] = acc * sc;
    }
}

// ---------------- edge kernel, layer 1 ----------------

__global__ __launch_bounds__(256) void k_edge1(const int* src_c, const int* dst_c,
        const float* dist_c, const float* sc_c,
        const float* vx_c, const float* vy_c, const float* vz_c,
        const ushort_t* qkvh, const ushort_t* Vih,
        const float* pw1, const float* pb1, const float* pw2, const float* pb2,
        float* aij) {
    __shared__ float s_w1[32 * 32], s_w2[32 * 16], s_b1[32], s_b2[16];
    int tid = threadIdx.x;
    for (int i = tid; i < 32 * 32; i += 256) s_w1[i] = pw1[i];
    for (int i = tid; i < 32 * 16; i += 256) s_w2[i] = pw2[i];
    if (tid < 32) s_b1[tid] = pb1[tid];
    if (tid < 16) s_b2[tid] = pb2[tid];
    __syncthreads();
    int i = blockIdx.x * 256 + tid;
    if (i >= N_EDGES) return;
    float d = dist_c[i], sc = sc_c[i];
    int s = src_c[i], t_ = dst_c[i];
    float ur[32];
    #pragma unroll
    for (int r = 0; r < 16; r++) {
        float cc = 0.8f + (float)r * RSTEP;
        float u  = (d - cc) * SIGINV;
        ur[r] = __expf(-u * u);
    }
    float Y[16];
    sph16(vx_c[i], vy_c[i], vz_c[i], Y);
    const uint4* vd4 = (const uint4*)(Vih + (size_t)t_ * 64);
    const uint4* vs4 = (const uint4*)(Vih + (size_t)s  * 64);
    #pragma unroll
    for (int th = 0; th < THH; th++) {
        float fd[16], fs[16];
        unpack8(vd4[2*th],   fd);     unpack8(vd4[2*th+1], fd+8);
        unpack8(vs4[2*th],   fs);     unpack8(vs4[2*th+1], fs+8);
        float us0 = (fd[0] + fs[0]) * Y[0];
        float us1 = 0.0f, us2 = 0.0f, us3 = 0.0f;
        #pragma unroll
        for (int m = 1; m < 4; m++)  us1 += (fd[m] - fs[m]) * Y[m];
        #pragma unroll
        for (int m = 4; m < 9; m++)  us2 += (fd[m] + fs[m]) * Y[m];
        #pragma unroll
        for (int m = 9; m < 16; m++) us3 += (fd[m] - fs[m]) * Y[m];
        ur[16 + 0 * 4 + th] = us0;
        ur[16 + 1 * 4 + th] = us1;
        ur[16 + 2 * 4 + th] = us2;
        ur[16 + 3 * 4 + th] = us3;
    }
    float wd[16];
    #pragma unroll
    for (int dd = 0; dd < 16; dd++) wd[dd] = s_b2[dd];
    for (int j = 0; j < 32; j++) {
        float a = s_b1[j];
        #pragma unroll
        for (int r = 0; r < 32; r++) a += ur[r] * s_w1[r * 32 + j];
        float sj = a / (1.0f + __expf(-a));
        #pragma unroll
        for (int dd = 0; dd < 16; dd++) wd[dd] += sj * s_w2[j * 16 + dd];
    }
    const uint4* q4 = (const uint4*)(qkvh + (size_t)t_ * QKV_W);
    const uint4* k4 = (const uint4*)(qkvh + (size_t)s  * QKV_W + QK_W);
    for (int h = 0; h < NH; h++) {
        float qa[8], qb[8], ka[8], kb[8];
        unpack8(q4[2*h],   qa); unpack8(q4[2*h+1], qb);
        unpack8(k4[2*h],   ka); unpack8(k4[2*h+1], kb);
        float acc = 0.0f;
        #pragma unroll
        for (int dd = 0; dd < 8; dd++) acc += qa[dd] * ka[dd] * wd[dd];
        #pragma unroll
        for (int dd = 0; dd < 8; dd++) acc += qb[dd] * kb[dd] * wd[8 + dd];
        aij[(size_t)i * NH + h] = acc * sc;
    }
}

// ---------------- aggregation, layer 0: mi (bf16 -> cxm) and Vi (bf16) ----------------

__global__ __launch_bounds__(256) void k_agg0(const int* off, const int* src_c,
        const float* vx_c, const float* vy_c, const float* vz_c,
        const float* aij, const ushort_t* qkvh,
        ushort_t* cxm, ushort_t* Vih) {
    int n = blockIdx.x;
    int tid = threadIdx.x;
    int start = off[n], end = off[n + 1];
    float acc = 0.0f;
    if (tid < DIM) {
        int h = tid / VD;
        for (int i = start; i < end; i++) {
            int s = src_c[i];
            float vv = __uint_as_float(((unsigned)qkvh[(size_t)s * QKV_W + 640 + tid]) << 16);
            acc += aij[(size_t)i * NH + h] * vv;
        }
        cxm[(size_t)n * UI_W + DIM + tid] = f2bf(acc);
    } else if (tid < DIM + 64) {
        int u = tid - DIM;
        int th = u >> 4, sm = u & 15;
        for (int i = start; i < end; i++) {
            float Y[16];
            sph16(vx_c[i], vy_c[i], vz_c[i], Y);
            acc += aij[(size_t)i * NH + SH_HEADS + th] * sel16(Y, sm);
        }
        Vih[(size_t)n * 64 + u] = f2bf(acc);
    }
}

// ---------------- aggregation, layer 1: mi only ----------------

__global__ __launch_bounds__(256) void k_agg1(const int* off, const int* src_c,
        const float* aij, const ushort_t* qkvh, ushort_t* cxm) {
    int n = blockIdx.x;
    int tid = threadIdx.x;
    if (tid >= DIM) return;
    int start = off[n], end = off[n + 1];
    int h = tid / VD;
    float acc = 0.0f;
    for (int i = start; i < end; i++) {
        int s = src_c[i];
        float vv = __uint_as_float(((unsigned)qkvh[(size_t)s * QKV_W + 640 + tid]) << 16);
        acc += aij[(size_t)i * NH + h] * vv;
    }
    cxm[(size_t)n * UI_W + DIM + tid] = f2bf(acc);
}

// ---------------- LN epilogue: xo = LN(xi + yg + ub); also bf16 copies ----------------

__global__ __launch_bounds__(256) void k_lnfinal(const float* yg, const float* xi,
        const float* ub, float* xo, ushort_t* xib, ushort_t* cxm) {
    __shared__ float yt[16 * DIM];
    __shared__ float red[256];
    __shared__ float mus[16], rstds[16];
    int base = blockIdx.x * 16;
    int tid  = threadIdx.x;
    for (int idx = tid; idx < 16 * DIM; idx += 256) {
        int n = idx / DIM, c = idx - n * DIM;
        yt[idx] = xi[(size_t)(base + n) * DIM + c] + yg[(size_t)(base + n) * DIM + c] + ub[c];
    }
    __syncthreads();
    { int n2 = tid >> 4, j = tid & 15;
      float s = 0.0f;
      for (int c2 = j; c2 < DIM; c2 += 16) s += yt[n2 * DIM + c2];
      red[tid] = s; }
    __syncthreads();
    if (tid < 16) { float s = 0; for (int j = 0; j < 16; j++) s += red[tid * 16 + j]; mus[tid] = s / (float)DIM; }
    __syncthreads();
    { int n2 = tid >> 4, j = tid & 15;
      float mu = mus[n2], s = 0.0f;
      for (int c2 = j; c2 < DIM; c2 += 16) { float d = yt[n2 * DIM + c2] - mu; s += d * d; }
      red[tid] = s; }
    __syncthreads();
    if (tid < 16) { float s = 0; for (int j = 0; j < 16; j++) s += red[tid * 16 + j]; rstds[tid] = rsqrtf(s / (float)DIM + 1e-6f); }
    __syncthreads();
    int c = tid;
    if (c < DIM) {
        #pragma unroll
        for (int n = 0; n < 16; n++) {
            float val = (yt[n * DIM + c] - mus[n]) * rstds[n];
            xo[(size_t)(base + n) * DIM + c] = val;
            ushort_t bv = f2bf(val);
            xib[(size_t)(base + n) * KQ + c]   = bv;
            cxm[(size_t)(base + n) * UI_W + c] = bv;
        }
    } else if (c < KQ) {
        #pragma unroll
        for (int n = 0; n < 16; n++) xib[(size_t)(base + n) * KQ + c] = 0;
    }
}

// ---------------- launch ----------------

extern "C" void kernel_launch(void* const* d_in, const int* in_sizes, int n_in,
                              void* d_out, int out_size, void* d_ws, size_t ws_size,
                              hipStream_t stream) {
    const int*   species = (const int*)  d_in[0];
    const float* dist    = (const float*)d_in[1];
    const float* swit    = (const float*)d_in[2];
    const int*   esrc    = (const int*)  d_in[3];
    const int*   edst    = (const int*)  d_in[4];
    const float* vec     = (const float*)d_in[5];
    const float* z_table = (const float*)d_in[6];
    const float* wsp     = (const float*)d_in[7];
    const float* pw1_0 = (const float*)d_in[8],  *pb1_0 = (const float*)d_in[9];
    const float* pw2_0 = (const float*)d_in[10], *pb2_0 = (const float*)d_in[11];
    const float* wq0 = (const float*)d_in[12], *wk0 = (const float*)d_in[13];
    const float* wv0 = (const float*)d_in[14], *uw0 = (const float*)d_in[15];
    const float* ub0 = (const float*)d_in[16];
    const float* pw1_1 = (const float*)d_in[17], *pb1_1 = (const float*)d_in[18];
    const float* pw2_1 = (const float*)d_in[19], *pb2_1 = (const float*)d_in[20];
    const float* wq1 = (const float*)d_in[21], *wk1 = (const float*)d_in[22];
    const float* wv1 = (const float*)d_in[23], *uw1 = (const float*)d_in[24];
    const float* ub1 = (const float*)d_in[25];
    float* out = (float*)d_out;

    char* p = (char*)d_ws;
    auto alloc = [&](size_t bytes) -> char* {
        char* r = p;
        p += (bytes + 255) & ~(size_t)255;
        return r;
    };
    int* deg    = (int*)alloc((size_t)N_NODES * 4);
    int* off    = (int*)alloc((size_t)(N_NODES + 1) * 4);
    int* cursor = (int*)alloc((size_t)N_NODES * 4);
    int* elist  = (int*)alloc((size_t)N_EDGES * 4);
    int*   src_c  = (int*)  alloc((size_t)N_EDGES * 4);
    int*   dst_c  = (int*)  alloc((size_t)N_EDGES * 4);
    float* dist_c = (float*)alloc((size_t)N_EDGES * 4);
    float* sc_c   = (float*)alloc((size_t)N_EDGES * 4);
    float* vx_c   = (float*)alloc((size_t)N_EDGES * 4);
    float* vy_c   = (float*)alloc((size_t)N_EDGES * 4);
    float* vz_c   = (float*)alloc((size_t)N_EDGES * 4);
    float* xiA  = (float*)alloc((size_t)N_NODES * DIM * 4);
    float* xiB  = (float*)alloc((size_t)N_NODES * DIM * 4);
    ushort_t* xib  = (ushort_t*)alloc((size_t)N_PAD * KQ * 2);
    ushort_t* cxm  = (ushort_t*)alloc((size_t)N_PAD * UI_W * 2);
    ushort_t* qkvh = (ushort_t*)alloc((size_t)N_NODES * QKV_W * 2);
    float* ybuf    = (float*)alloc((size_t)N_NODES * DIM * 4);
    ushort_t* Wtq0 = (ushort_t*)alloc((size_t)832 * KQ * 2);
    ushort_t* Wtq1 = (ushort_t*)alloc((size_t)832 * KQ * 2);
    ushort_t* Wtu0 = (ushort_t*)alloc((size_t)192 * UI_W * 2);
    ushort_t* Wtu1 = (ushort_t*)alloc((size_t)192 * UI_W * 2);
    ushort_t* Vih  = (ushort_t*)alloc((size_t)N_NODES * 64 * 2);
    float* aij  = (float*)alloc((size_t)N_EDGES * NH * 4);

    const int NB_N  = (N_NODES + 255) / 256;
    const int NB_E  = (N_EDGES + 255) / 256;
    const int NB_T  = N_NODES / 16;   // 625
    const dim3 GRID_QKV(13, 157);     // 816/64 ceil x 10048/64
    const dim3 GRID_UPD(3, 157);      // 176/64 ceil

    k_zero<<<NB_N, 256, 0, stream>>>(deg);
    k_deg<<<NB_E, 256, 0, stream>>>(edst, deg);
    k_scan<<<1, 1024, 0, stream>>>(deg, off, cursor);
    k_scatter<<<NB_E, 256, 0, stream>>>(edst, cursor, elist);
    k_reorder<<<NB_E, 256, 0, stream>>>(elist, esrc, edst, dist, swit, vec,
                                        src_c, dst_c, dist_c, sc_c, vx_c, vy_c, vz_c);

    k_prep_qkv<<<624, 256, 0, stream>>>(wq0, wk0, wv0, Wtq0);
    k_prep_qkv<<<624, 256, 0, stream>>>(wq1, wk1, wv1, Wtq1);
    k_prep_upd<<<264, 256, 0, stream>>>(uw0, Wtu0);
    k_prep_upd<<<264, 256, 0, stream>>>(uw1, Wtu1);

    k_node_init<<<NB_T, 256, 0, stream>>>(species, z_table, wsp, xiA, xib, cxm);

    // layer 0
    k_gemm<6, true><<<GRID_QKV, 256, 0, stream>>>(xib, KQ, Wtq0, KQ, qkvh, QKV_W,
                                                  N_NODES, QKV_W);
    k_edge0<<<NB_E, 256, 0, stream>>>(src_c, dst_c, dist_c, sc_c, qkvh,
                                      pw1_0, pb1_0, pw2_0, pb2_0, aij);
    k_agg0<<<N_NODES, 256, 0, stream>>>(off, src_c, vx_c, vy_c, vz_c, aij, qkvh, cxm, Vih);
    k_gemm<11, false><<<GRID_UPD, 256, 0, stream>>>(cxm, UI_W, Wtu0, UI_W, ybuf, DIM,
                                                    N_NODES, DIM);
    k_lnfinal<<<NB_T, 256, 0, stream>>>(ybuf, xiA, ub0, xiB, xib, cxm);

    // layer 1
    k_gemm<6, true><<<GRID_QKV, 256, 0, stream>>>(xib, KQ, Wtq1, KQ, qkvh, QKV_W,
                                                  N_NODES, QKV_W);
    k_edge1<<<NB_E, 256, 0, stream>>>(src_c, dst_c, dist_c, sc_c, vx_c, vy_c, vz_c,
                                      qkvh, Vih, pw1_1, pb1_1, pw2_1, pb2_1, aij);
    k_agg1<<<N_NODES, 256, 0, stream>>>(off, src_c, aij, qkvh, cxm);
    k_gemm<11, false><<<GRID_UPD, 256, 0, stream>>>(cxm, UI_W, Wtu1, UI_W, ybuf, DIM,
                                                    N_NODES, DIM);
    k_lnfinal<<<NB_T, 256, 0, stream>>>(ybuf, xiB, ub1, out, xib, cxm);
}

// Round 5
// 545.000 us; speedup vs baseline: 3.2863x; 1.1989x over previous
//
#include <hip/hip_runtime.h>
#include <hip/hip_bf16.h>
#include <math.h>

#define N_NODES 10000
#define N_PAD   10048       // 157 * 64
#define N_EDGES 320000
#define DIM     176
#define ATT     16
#define SH_HEADS 16
#define THH     4
#define NH      20          // SH_HEADS + TH
#define VD      11          // DIM / SH_HEADS
#define ZDIM    16
#define RDIM    16
#define QK_W    (NH*ATT)    // 320
#define QKV_W   816         // 320+320+176
#define UI_W    (2*DIM)     // 352
#define KQ      192         // padded K for qkv gemm
#define SIGINV  3.5714285714285716f   // (RDIM-1)/(CUT-RSTART)
#define RSTEP   0.28f                 // (CUT-RSTART)/(RDIM-1)

typedef unsigned short ushort_t;
typedef __attribute__((ext_vector_type(8))) short bf16x8;
typedef __attribute__((ext_vector_type(4))) float f32x4;

// ---------------- helpers ----------------

__device__ __forceinline__ ushort_t f2bf(float f) {
    __hip_bfloat16 b = __float2bfloat16(f);
    return *(ushort_t*)&b;
}

__device__ __forceinline__ void sph16(float x, float y, float z, float* Y) {
    const float s3  = 1.7320508075688772f;
    const float s15 = 3.872983346207417f;
    const float c1  = 0.7905694150420949f;
    const float c2  = 0.6123724356957945f;
    float x2 = x*x, y2 = y*y, z2 = z*z;
    Y[0]  = 1.0f;
    Y[1]  = x;
    Y[2]  = y;
    Y[3]  = z;
    Y[4]  = s3 * x * y;
    Y[5]  = s3 * y * z;
    Y[6]  = 0.5f * (3.0f * z2 - 1.0f);
    Y[7]  = s3 * x * z;
    Y[8]  = 0.5f * s3 * (x2 - y2);
    Y[9]  = c1 * y * (3.0f * x2 - y2);
    Y[10] = s15 * x * y * z;
    Y[11] = c2 * y * (5.0f * z2 - 1.0f);
    Y[12] = 0.5f * z * (5.0f * z2 - 3.0f);
    Y[13] = c2 * x * (5.0f * z2 - 1.0f);
    Y[14] = 0.5f * s15 * z * (x2 - y2);
    Y[15] = c1 * x * (x2 - 3.0f * y2);
}

__device__ __forceinline__ float sel16(const float* Y, int i) {
    float a0 = (i & 1) ? Y[1]  : Y[0];
    float a1 = (i & 1) ? Y[3]  : Y[2];
    float a2 = (i & 1) ? Y[5]  : Y[4];
    float a3 = (i & 1) ? Y[7]  : Y[6];
    float a4 = (i & 1) ? Y[9]  : Y[8];
    float a5 = (i & 1) ? Y[11] : Y[10];
    float a6 = (i & 1) ? Y[13] : Y[12];
    float a7 = (i & 1) ? Y[15] : Y[14];
    float b0 = (i & 2) ? a1 : a0;
    float b1 = (i & 2) ? a3 : a2;
    float b2 = (i & 2) ? a5 : a4;
    float b3 = (i & 2) ? a7 : a6;
    float c0 = (i & 4) ? b1 : b0;
    float c1 = (i & 4) ? b3 : b2;
    return (i & 8) ? c1 : c0;
}

__device__ __forceinline__ void unpack8(const uint4 u, float* f) {
    f[0] = __uint_as_float(u.x << 16);
    f[1] = __uint_as_float(u.x & 0xffff0000u);
    f[2] = __uint_as_float(u.y << 16);
    f[3] = __uint_as_float(u.y & 0xffff0000u);
    f[4] = __uint_as_float(u.z << 16);
    f[5] = __uint_as_float(u.z & 0xffff0000u);
    f[6] = __uint_as_float(u.w << 16);
    f[7] = __uint_as_float(u.w & 0xffff0000u);
}

// ---------------- CSR build ----------------

__global__ __launch_bounds__(256) void k_zero(int* deg) {
    int i = blockIdx.x * 256 + threadIdx.x;
    if (i < N_NODES) deg[i] = 0;
}

__global__ __launch_bounds__(256) void k_deg(const int* edst, int* deg) {
    int e = blockIdx.x * 256 + threadIdx.x;
    if (e < N_EDGES) atomicAdd(&deg[edst[e]], 1);
}

__global__ __launch_bounds__(1024) void k_scan(const int* deg, int* off, int* cursor) {
    __shared__ int sd[1024];
    __shared__ int carry;
    int tid = threadIdx.x;
    if (tid == 0) { off[0] = 0; carry = 0; }
    __syncthreads();
    for (int b0 = 0; b0 < N_NODES; b0 += 1024) {
        int v = (b0 + tid < N_NODES) ? deg[b0 + tid] : 0;
        sd[tid] = v;
        __syncthreads();
        for (int s = 1; s < 1024; s <<= 1) {
            int add = (tid >= s) ? sd[tid - s] : 0;
            __syncthreads();
            sd[tid] += add;
            __syncthreads();
        }
        int incl = sd[tid];
        if (b0 + tid < N_NODES) {
            off[b0 + tid + 1]  = carry + incl;
            cursor[b0 + tid]   = carry + incl - v;
        }
        __syncthreads();
        if (tid == 0) carry += sd[1023];
        __syncthreads();
    }
}

__global__ __launch_bounds__(256) void k_scatter(const int* edst, int* cursor, int* elist) {
    int e = blockIdx.x * 256 + threadIdx.x;
    if (e < N_EDGES) {
        int p = atomicAdd(&cursor[edst[e]], 1);
        elist[p] = e;
    }
}

__global__ __launch_bounds__(256) void k_reorder(const int* elist, const int* esrc, const int* edst,
        const float* dist, const float* swit, const float* vec,
        int* src_c, int* dst_c, float* dist_c, float* sc_c,
        float* vx_c, float* vy_c, float* vz_c) {
    int i = blockIdx.x * 256 + threadIdx.x;
    if (i >= N_EDGES) return;
    int e = elist[i];
    float d = dist[e];
    float inv = 1.0f / d;
    src_c[i]  = esrc[e];
    dst_c[i]  = edst[e];
    dist_c[i] = d;
    sc_c[i]   = swit[e] * 0.25f;           // switch / sqrt(ATT)
    vx_c[i]   = vec[(size_t)e*3 + 0] * inv;
    vy_c[i]   = vec[(size_t)e*3 + 1] * inv;
    vz_c[i]   = vec[(size_t)e*3 + 2] * inv;
}

// ---------------- weight prep (fp32 -> transposed bf16, padded) ----------------

__global__ __launch_bounds__(256) void k_prep_qkv(const float* wq, const float* wk,
                                                  const float* wv, ushort_t* Wtq) {
    int id = blockIdx.x * 256 + threadIdx.x;
    if (id >= 192 * 832) return;
    int k = id / 832, n = id - (id / 832) * 832;
    float v = 0.0f;
    if (k < DIM && n < QKV_W)
        v = (n < 320) ? wq[k * 320 + n] : (n < 640) ? wk[k * 320 + (n - 320)]
                                                    : wv[k * DIM + (n - 640)];
    Wtq[(size_t)n * KQ + k] = f2bf(v);
}

__global__ __launch_bounds__(256) void k_prep_upd(const float* uw, ushort_t* Wtu) {
    int id = blockIdx.x * 256 + threadIdx.x;
    if (id >= 352 * 192) return;
    int k = id / 192, n = id - (id / 192) * 192;
    float v = (n < DIM) ? uw[k * DIM + n] : 0.0f;
    Wtu[(size_t)n * UI_W + k] = f2bf(v);
}

// ---------------- MFMA GEMM: C[M x N] = A[M x K] @ Bt[N x K]^T ----------------

template<int KCHUNKS, bool BF16OUT>
__global__ __launch_bounds__(256) void k_gemm(const ushort_t* __restrict__ A, int sA,
                                              const ushort_t* __restrict__ Bt, int sB,
                                              void* __restrict__ Cv, int sC, int M, int N) {
    __shared__ ushort_t As[64 * 40];   // +8 pad breaks b128 bank aliasing
    __shared__ ushort_t Bs[64 * 40];
    int tid  = threadIdx.x;
    int m0   = blockIdx.y * 64, n0 = blockIdx.x * 64;
    int w    = tid >> 6, lane = tid & 63, quad = lane >> 4, c16 = lane & 15;
    int arow = tid >> 2, aseg = tid & 3;
    f32x4 acc[4] = {};
    for (int kc = 0; kc < KCHUNKS; kc++) {
        int k0 = kc * 32;
        *(uint4*)&As[arow * 40 + aseg * 8] =
            *(const uint4*)&A[(size_t)(m0 + arow) * sA + k0 + aseg * 8];
        *(uint4*)&Bs[arow * 40 + aseg * 8] =
            *(const uint4*)&Bt[(size_t)(n0 + arow) * sB + k0 + aseg * 8];
        __syncthreads();
        bf16x8 a = *(const bf16x8*)&As[(w * 16 + c16) * 40 + quad * 8];
        #pragma unroll
        for (int t = 0; t < 4; t++) {
            bf16x8 b = *(const bf16x8*)&Bs[(t * 16 + c16) * 40 + quad * 8];
            acc[t] = __builtin_amdgcn_mfma_f32_16x16x32_bf16(a, b, acc[t], 0, 0, 0);
        }
        __syncthreads();
    }
    #pragma unroll
    for (int t = 0; t < 4; t++) {
        #pragma unroll
        for (int r = 0; r < 4; r++) {
            int row = m0 + w * 16 + quad * 4 + r;
            int col = n0 + t * 16 + c16;
            if (row < M && col < N) {
                if (BF16OUT)
                    ((ushort_t*)Cv)[(size_t)row * sC + col] = f2bf(acc[t][r]);
                else
                    ((float*)Cv)[(size_t)row * sC + col] = acc[t][r];
            }
        }
    }
}

// ---------------- node embedding ----------------

__global__ __launch_bounds__(256) void k_node_init(const int* species, const float* z_table,
                                                   const float* wsp, float* xi,
                                                   ushort_t* xib, ushort_t* cxm) {
    __shared__ float zs[16 * ZDIM];
    __shared__ float yt[16 * DIM];
    __shared__ float red[256];
    __shared__ float mus[16], rstds[16];
    int base = blockIdx.x * 16;
    int tid  = threadIdx.x;
    { int n = tid >> 4, kk = tid & 15;
      zs[tid] = z_table[species[base + n] * ZDIM + kk]; }
    __syncthreads();
    int c = tid;
    if (c < DIM) {
        float acc[16];
        #pragma unroll
        for (int n = 0; n < 16; n++) acc[n] = 0.0f;
        for (int kk = 0; kk < ZDIM; kk++) {
            float w = wsp[kk * DIM + c];
            #pragma unroll
            for (int n = 0; n < 16; n++) acc[n] += zs[n * ZDIM + kk] * w;
        }
        #pragma unroll
        for (int n = 0; n < 16; n++) yt[n * DIM + c] = acc[n];
    }
    __syncthreads();
    { int n2 = tid >> 4, j = tid & 15;
      float s = 0.0f;
      for (int c2 = j; c2 < DIM; c2 += 16) s += yt[n2 * DIM + c2];
      red[tid] = s; }
    __syncthreads();
    if (tid < 16) { float s = 0; for (int j = 0; j < 16; j++) s += red[tid * 16 + j]; mus[tid] = s / (float)DIM; }
    __syncthreads();
    { int n2 = tid >> 4, j = tid & 15;
      float mu = mus[n2], s = 0.0f;
      for (int c2 = j; c2 < DIM; c2 += 16) { float d = yt[n2 * DIM + c2] - mu; s += d * d; }
      red[tid] = s; }
    __syncthreads();
    if (tid < 16) { float s = 0; for (int j = 0; j < 16; j++) s += red[tid * 16 + j]; rstds[tid] = rsqrtf(s / (float)DIM + 1e-6f); }
    __syncthreads();
    if (c < DIM) {
        #pragma unroll
        for (int n = 0; n < 16; n++) {
            float val = (yt[n * DIM + c] - mus[n]) * rstds[n];
            xi[(size_t)(base + n) * DIM + c] = val;
            ushort_t bv = f2bf(val);
            xib[(size_t)(base + n) * KQ + c]   = bv;
            cxm[(size_t)(base + n) * UI_W + c] = bv;
        }
    } else if (c < KQ) {
        #pragma unroll
        for (int n = 0; n < 16; n++) xib[(size_t)(base + n) * KQ + c] = 0;
    }
}

// ---------------- edge kernel, layer 0 (SoA aij[h][edge]) ----------------

__global__ __launch_bounds__(256) void k_edge0(const int* src_c, const int* dst_c,
        const float* dist_c, const float* sc_c,
        const ushort_t* qkvh,
        const float* pw1, const float* pb1, const float* pw2, const float* pb2,
        float* aij) {
    __shared__ float s_w1[RDIM * 32], s_w2[32 * 16], s_b1[32], s_b2[16];
    int tid = threadIdx.x;
    for (int i = tid; i < RDIM * 32; i += 256) s_w1[i] = pw1[i];
    for (int i = tid; i < 32 * 16; i += 256) s_w2[i] = pw2[i];
    if (tid < 32) s_b1[tid] = pb1[tid];
    if (tid < 16) s_b2[tid] = pb2[tid];
    __syncthreads();
    int i = blockIdx.x * 256 + tid;
    if (i >= N_EDGES) return;
    float d = dist_c[i], sc = sc_c[i];
    int s = src_c[i], t_ = dst_c[i];
    float ur[RDIM];
    #pragma unroll
    for (int r = 0; r < 16; r++) {
        float cc = 0.8f + (float)r * RSTEP;
        float u  = (d - cc) * SIGINV;
        ur[r] = __expf(-u * u);
    }
    float wd[16];
    #pragma unroll
    for (int dd = 0; dd < 16; dd++) wd[dd] = s_b2[dd];
    for (int j = 0; j < 32; j++) {
        float a = s_b1[j];
        #pragma unroll
        for (int r = 0; r < 16; r++) a += ur[r] * s_w1[r * 32 + j];
        float sj = a / (1.0f + __expf(-a));
        #pragma unroll
        for (int dd = 0; dd < 16; dd++) wd[dd] += sj * s_w2[j * 16 + dd];
    }
    const uint4* q4 = (const uint4*)(qkvh + (size_t)t_ * QKV_W);
    const uint4* k4 = (const uint4*)(qkvh + (size_t)s  * QKV_W + QK_W);
    for (int h = 0; h < NH; h++) {
        float qa[8], qb[8], ka[8], kb[8];
        unpack8(q4[2*h],   qa); unpack8(q4[2*h+1], qb);
        unpack8(k4[2*h],   ka); unpack8(k4[2*h+1], kb);
        float acc = 0.0f;
        #pragma unroll
        for (int dd = 0; dd < 8; dd++) acc += qa[dd] * ka[dd] * wd[dd];
        #pragma unroll
        for (int dd = 0; dd < 8; dd++) acc += qb[dd] * kb[dd] * wd[8 + dd];
        aij[(size_t)h * N_EDGES + i] = acc * sc;   // SoA: coalesced per h
    }
}

// ---------------- edge kernel, layer 1 (SoA aij[h][edge]) ----------------

__global__ __launch_bounds__(256) void k_edge1(const int* src_c, const int* dst_c,
        const float* dist_c, const float* sc_c,
        const float* vx_c, const float* vy_c, const float* vz_c,
        const ushort_t* qkvh, const ushort_t* Vih,
        const float* pw1, const float* pb1, const float* pw2, const float* pb2,
        float* aij) {
    __shared__ float s_w1[32 * 32], s_w2[32 * 16], s_b1[32], s_b2[16];
    int tid = threadIdx.x;
    for (int i = tid; i < 32 * 32; i += 256) s_w1[i] = pw1[i];
    for (int i = tid; i < 32 * 16; i += 256) s_w2[i] = pw2[i];
    if (tid < 32) s_b1[tid] = pb1[tid];
    if (tid < 16) s_b2[tid] = pb2[tid];
    __syncthreads();
    int i = blockIdx.x * 256 + tid;
    if (i >= N_EDGES) return;
    float d = dist_c[i], sc = sc_c[i];
    int s = src_c[i], t_ = dst_c[i];
    float ur[32];
    #pragma unroll
    for (int r = 0; r < 16; r++) {
        float cc = 0.8f + (float)r * RSTEP;
        float u  = (d - cc) * SIGINV;
        ur[r] = __expf(-u * u);
    }
    float Y[16];
    sph16(vx_c[i], vy_c[i], vz_c[i], Y);
    const uint4* vd4 = (const uint4*)(Vih + (size_t)t_ * 64);
    const uint4* vs4 = (const uint4*)(Vih + (size_t)s  * 64);
    #pragma unroll
    for (int th = 0; th < THH; th++) {
        float fd[16], fs[16];
        unpack8(vd4[2*th],   fd);     unpack8(vd4[2*th+1], fd+8);
        unpack8(vs4[2*th],   fs);     unpack8(vs4[2*th+1], fs+8);
        float us0 = (fd[0] + fs[0]) * Y[0];
        float us1 = 0.0f, us2 = 0.0f, us3 = 0.0f;
        #pragma unroll
        for (int m = 1; m < 4; m++)  us1 += (fd[m] - fs[m]) * Y[m];
        #pragma unroll
        for (int m = 4; m < 9; m++)  us2 += (fd[m] + fs[m]) * Y[m];
        #pragma unroll
        for (int m = 9; m < 16; m++) us3 += (fd[m] - fs[m]) * Y[m];
        ur[16 + 0 * 4 + th] = us0;
        ur[16 + 1 * 4 + th] = us1;
        ur[16 + 2 * 4 + th] = us2;
        ur[16 + 3 * 4 + th] = us3;
    }
    float wd[16];
    #pragma unroll
    for (int dd = 0; dd < 16; dd++) wd[dd] = s_b2[dd];
    for (int j = 0; j < 32; j++) {
        float a = s_b1[j];
        #pragma unroll
        for (int r = 0; r < 32; r++) a += ur[r] * s_w1[r * 32 + j];
        float sj = a / (1.0f + __expf(-a));
        #pragma unroll
        for (int dd = 0; dd < 16; dd++) wd[dd] += sj * s_w2[j * 16 + dd];
    }
    const uint4* q4 = (const uint4*)(qkvh + (size_t)t_ * QKV_W);
    const uint4* k4 = (const uint4*)(qkvh + (size_t)s  * QKV_W + QK_W);
    for (int h = 0; h < NH; h++) {
        float qa[8], qb[8], ka[8], kb[8];
        unpack8(q4[2*h],   qa); unpack8(q4[2*h+1], qb);
        unpack8(k4[2*h],   ka); unpack8(k4[2*h+1], kb);
        float acc = 0.0f;
        #pragma unroll
        for (int dd = 0; dd < 8; dd++) acc += qa[dd] * ka[dd] * wd[dd];
        #pragma unroll
        for (int dd = 0; dd < 8; dd++) acc += qb[dd] * kb[dd] * wd[8 + dd];
        aij[(size_t)h * N_EDGES + i] = acc * sc;   // SoA: coalesced per h
    }
}

// ---------------- aggregation, layer 0 (SoA aij) ----------------

__global__ __launch_bounds__(256) void k_agg0(const int* off, const int* src_c,
        const float* vx_c, const float* vy_c, const float* vz_c,
        const float* aij, const ushort_t* qkvh,
        ushort_t* cxm, ushort_t* Vih) {
    int n = blockIdx.x;
    int tid = threadIdx.x;
    int start = off[n], end = off[n + 1];
    float acc = 0.0f;
    if (tid < DIM) {
        int h = tid / VD;
        const float* ah = aij + (size_t)h * N_EDGES;
        for (int i = start; i < end; i++) {
            int s = src_c[i];
            float vv = __uint_as_float(((unsigned)qkvh[(size_t)s * QKV_W + 640 + tid]) << 16);
            acc += ah[i] * vv;
        }
        cxm[(size_t)n * UI_W + DIM + tid] = f2bf(acc);
    } else if (tid < DIM + 64) {
        int u = tid - DIM;
        int th = u >> 4, sm = u & 15;
        const float* ah = aij + (size_t)(SH_HEADS + th) * N_EDGES;
        for (int i = start; i < end; i++) {
            float Y[16];
            sph16(vx_c[i], vy_c[i], vz_c[i], Y);
            acc += ah[i] * sel16(Y, sm);
        }
        Vih[(size_t)n * 64 + u] = f2bf(acc);
    }
}

// ---------------- aggregation, layer 1 (SoA aij) ----------------

__global__ __launch_bounds__(256) void k_agg1(const int* off, const int* src_c,
        const float* aij, const ushort_t* qkvh, ushort_t* cxm) {
    int n = blockIdx.x;
    int tid = threadIdx.x;
    if (tid >= DIM) return;
    int start = off[n], end = off[n + 1];
    int h = tid / VD;
    const float* ah = aij + (size_t)h * N_EDGES;
    float acc = 0.0f;
    for (int i = start; i < end; i++) {
        int s = src_c[i];
        float vv = __uint_as_float(((unsigned)qkvh[(size_t)s * QKV_W + 640 + tid]) << 16);
        acc += ah[i] * vv;
    }
    cxm[(size_t)n * UI_W + DIM + tid] = f2bf(acc);
}

// ---------------- LN epilogue ----------------

__global__ __launch_bounds__(256) void k_lnfinal(const float* yg, const float* xi,
        const float* ub, float* xo, ushort_t* xib, ushort_t* cxm) {
    __shared__ float yt[16 * DIM];
    __shared__ float red[256];
    __shared__ float mus[16], rstds[16];
    int base = blockIdx.x * 16;
    int tid  = threadIdx.x;
    for (int idx = tid; idx < 16 * DIM; idx += 256) {
        int n = idx / DIM, c = idx - n * DIM;
        yt[idx] = xi[(size_t)(base + n) * DIM + c] + yg[(size_t)(base + n) * DIM + c] + ub[c];
    }
    __syncthreads();
    { int n2 = tid >> 4, j = tid & 15;
      float s = 0.0f;
      for (int c2 = j; c2 < DIM; c2 += 16) s += yt[n2 * DIM + c2];
      red[tid] = s; }
    __syncthreads();
    if (tid < 16) { float s = 0; for (int j = 0; j < 16; j++) s += red[tid * 16 + j]; mus[tid] = s / (float)DIM; }
    __syncthreads();
    { int n2 = tid >> 4, j = tid & 15;
      float mu = mus[n2], s = 0.0f;
      for (int c2 = j; c2 < DIM; c2 += 16) { float d = yt[n2 * DIM + c2] - mu; s += d * d; }
      red[tid] = s; }
    __syncthreads();
    if (tid < 16) { float s = 0; for (int j = 0; j < 16; j++) s += red[tid * 16 + j]; rstds[tid] = rsqrtf(s / (float)DIM + 1e-6f); }
    __syncthreads();
    int c = tid;
    if (c < DIM) {
        #pragma unroll
        for (int n = 0; n < 16; n++) {
            float val = (yt[n * DIM + c] - mus[n]) * rstds[n];
            xo[(size_t)(base + n) * DIM + c] = val;
            ushort_t bv = f2bf(val);
            xib[(size_t)(base + n) * KQ + c]   = bv;
            cxm[(size_t)(base + n) * UI_W + c] = bv;
        }
    } else if (c < KQ) {
        #pragma unroll
        for (int n = 0; n < 16; n++) xib[(size_t)(base + n) * KQ + c] = 0;
    }
}

// ---------------- launch ----------------

extern "C" void kernel_launch(void* const* d_in, const int* in_sizes, int n_in,
                              void* d_out, int out_size, void* d_ws, size_t ws_size,
                              hipStream_t stream) {
    const int*   species = (const int*)  d_in[0];
    const float* dist    = (const float*)d_in[1];
    const float* swit    = (const float*)d_in[2];
    const int*   esrc    = (const int*)  d_in[3];
    const int*   edst    = (const int*)  d_in[4];
    const float* vec     = (const float*)d_in[5];
    const float* z_table = (const float*)d_in[6];
    const float* wsp     = (const float*)d_in[7];
    const float* pw1_0 = (const float*)d_in[8],  *pb1_0 = (const float*)d_in[9];
    const float* pw2_0 = (const float*)d_in[10], *pb2_0 = (const float*)d_in[11];
    const float* wq0 = (const float*)d_in[12], *wk0 = (const float*)d_in[13];
    const float* wv0 = (const float*)d_in[14], *uw0 = (const float*)d_in[15];
    const float* ub0 = (const float*)d_in[16];
    const float* pw1_1 = (const float*)d_in[17], *pb1_1 = (const float*)d_in[18];
    const float* pw2_1 = (const float*)d_in[19], *pb2_1 = (const float*)d_in[20];
    const float* wq1 = (const float*)d_in[21], *wk1 = (const float*)d_in[22];
    const float* wv1 = (const float*)d_in[23], *uw1 = (const float*)d_in[24];
    const float* ub1 = (const float*)d_in[25];
    float* out = (float*)d_out;

    char* p = (char*)d_ws;
    auto alloc = [&](size_t bytes) -> char* {
        char* r = p;
        p += (bytes + 255) & ~(size_t)255;
        return r;
    };
    int* deg    = (int*)alloc((size_t)N_NODES * 4);
    int* off    = (int*)alloc((size_t)(N_NODES + 1) * 4);
    int* cursor = (int*)alloc((size_t)N_NODES * 4);
    int* elist  = (int*)alloc((size_t)N_EDGES * 4);
    int*   src_c  = (int*)  alloc((size_t)N_EDGES * 4);
    int*   dst_c  = (int*)  alloc((size_t)N_EDGES * 4);
    float* dist_c = (float*)alloc((size_t)N_EDGES * 4);
    float* sc_c   = (float*)alloc((size_t)N_EDGES * 4);
    float* vx_c   = (float*)alloc((size_t)N_EDGES * 4);
    float* vy_c   = (float*)alloc((size_t)N_EDGES * 4);
    float* vz_c   = (float*)alloc((size_t)N_EDGES * 4);
    float* xiA  = (float*)alloc((size_t)N_NODES * DIM * 4);
    float* xiB  = (float*)alloc((size_t)N_NODES * DIM * 4);
    ushort_t* xib  = (ushort_t*)alloc((size_t)N_PAD * KQ * 2);
    ushort_t* cxm  = (ushort_t*)alloc((size_t)N_PAD * UI_W * 2);
    ushort_t* qkvh = (ushort_t*)alloc((size_t)N_NODES * QKV_W * 2);
    float* ybuf    = (float*)alloc((size_t)N_NODES * DIM * 4);
    ushort_t* Wtq0 = (ushort_t*)alloc((size_t)832 * KQ * 2);
    ushort_t* Wtq1 = (ushort_t*)alloc((size_t)832 * KQ * 2);
    ushort_t* Wtu0 = (ushort_t*)alloc((size_t)192 * UI_W * 2);
    ushort_t* Wtu1 = (ushort_t*)alloc((size_t)192 * UI_W * 2);
    ushort_t* Vih  = (ushort_t*)alloc((size_t)N_NODES * 64 * 2);
    float* aij  = (float*)alloc((size_t)N_EDGES * NH * 4);

    const int NB_N  = (N_NODES + 255) / 256;
    const int NB_E  = (N_EDGES + 255) / 256;
    const int NB_T  = N_NODES / 16;   // 625
    const dim3 GRID_QKV(13, 157);     // 816/64 ceil x 10048/64
    const dim3 GRID_UPD(3, 157);      // 176/64 ceil

    k_zero<<<NB_N, 256, 0, stream>>>(deg);
    k_deg<<<NB_E, 256, 0, stream>>>(edst, deg);
    k_scan<<<1, 1024, 0, stream>>>(deg, off, cursor);
    k_scatter<<<NB_E, 256, 0, stream>>>(edst, cursor, elist);
    k_reorder<<<NB_E, 256, 0, stream>>>(elist, esrc, edst, dist, swit, vec,
                                        src_c, dst_c, dist_c, sc_c, vx_c, vy_c, vz_c);

    k_prep_qkv<<<624, 256, 0, stream>>>(wq0, wk0, wv0, Wtq0);
    k_prep_qkv<<<624, 256, 0, stream>>>(wq1, wk1, wv1, Wtq1);
    k_prep_upd<<<264, 256, 0, stream>>>(uw0, Wtu0);
    k_prep_upd<<<264, 256, 0, stream>>>(uw1, Wtu1);

    k_node_init<<<NB_T, 256, 0, stream>>>(species, z_table, wsp, xiA, xib, cxm);

    // layer 0
    k_gemm<6, true><<<GRID_QKV, 256, 0, stream>>>(xib, KQ, Wtq0, KQ, qkvh, QKV_W,
                                                  N_NODES, QKV_W);
    k_edge0<<<NB_E, 256, 0, stream>>>(src_c, dst_c, dist_c, sc_c, qkvh,
                                      pw1_0, pb1_0, pw2_0, pb2_0, aij);
    k_agg0<<<N_NODES, 256, 0, stream>>>(off, src_c, vx_c, vy_c, vz_c, aij, qkvh, cxm, Vih);
    k_gemm<11, false><<<GRID_UPD, 256, 0, stream>>>(cxm, UI_W, Wtu0, UI_W, ybuf, DIM,
                                                    N_NODES, DIM);
    k_lnfinal<<<NB_T, 256, 0, stream>>>(ybuf, xiA, ub0, xiB, xib, cxm);

    // layer 1
    k_gemm<6, true><<<GRID_QKV, 256, 0, stream>>>(xib, KQ, Wtq1, KQ, qkvh, QKV_W,
                                                  N_NODES, QKV_W);
    k_edge1<<<NB_E, 256, 0, stream>>>(src_c, dst_c, dist_c, sc_c, vx_c, vy_c, vz_c,
                                      qkvh, Vih, pw1_1, pb1_1, pw2_1, pb2_1, aij);
    k_agg1<<<N_NODES, 256, 0, stream>>>(off, src_c, aij, qkvh, cxm);
    k_gemm<11, false><<<GRID_UPD, 256, 0, stream>>>(cxm, UI_W, Wtu1, UI_W, ybuf, DIM,
                                                    N_NODES, DIM);
    k_lnfinal<<<NB_T, 256, 0, stream>>>(ybuf, xiB, ub1, out, xib, cxm);
}

// Round 6
// 478.653 us; speedup vs baseline: 3.7419x; 1.1386x over previous
//
#include <hip/hip_runtime.h>
#include <hip/hip_bf16.h>
#include <math.h>

#define N_NODES 10000
#define N_PAD   10048       // 157 * 64
#define N_EDGES 320000
#define DIM     176
#define ATT     16
#define SH_HEADS 16
#define THH     4
#define NH      20          // SH_HEADS + TH
#define VD      11          // DIM / SH_HEADS
#define ZDIM    16
#define RDIM    16
#define QK_W    (NH*ATT)    // 320
#define QKV_W   816         // 320+320+176
#define UI_W    (2*DIM)     // 352
#define KQ      192         // padded K for qkv gemm
#define SIGINV  3.5714285714285716f   // (RDIM-1)/(CUT-RSTART)
#define RSTEP   0.28f                 // (CUT-RSTART)/(RDIM-1)

typedef unsigned short ushort_t;
typedef __attribute__((ext_vector_type(8))) short bf16x8;
typedef __attribute__((ext_vector_type(4))) float f32x4;

// ---------------- helpers ----------------

__device__ __forceinline__ ushort_t f2bf(float f) {
    __hip_bfloat16 b = __float2bfloat16(f);
    return *(ushort_t*)&b;
}

__device__ __forceinline__ void sph16(float x, float y, float z, float* Y) {
    const float s3  = 1.7320508075688772f;
    const float s15 = 3.872983346207417f;
    const float c1  = 0.7905694150420949f;
    const float c2  = 0.6123724356957945f;
    float x2 = x*x, y2 = y*y, z2 = z*z;
    Y[0]  = 1.0f;
    Y[1]  = x;
    Y[2]  = y;
    Y[3]  = z;
    Y[4]  = s3 * x * y;
    Y[5]  = s3 * y * z;
    Y[6]  = 0.5f * (3.0f * z2 - 1.0f);
    Y[7]  = s3 * x * z;
    Y[8]  = 0.5f * s3 * (x2 - y2);
    Y[9]  = c1 * y * (3.0f * x2 - y2);
    Y[10] = s15 * x * y * z;
    Y[11] = c2 * y * (5.0f * z2 - 1.0f);
    Y[12] = 0.5f * z * (5.0f * z2 - 3.0f);
    Y[13] = c2 * x * (5.0f * z2 - 1.0f);
    Y[14] = 0.5f * s15 * z * (x2 - y2);
    Y[15] = c1 * x * (x2 - 3.0f * y2);
}

__device__ __forceinline__ void unpack8(const uint4 u, float* f) {
    f[0] = __uint_as_float(u.x << 16);
    f[1] = __uint_as_float(u.x & 0xffff0000u);
    f[2] = __uint_as_float(u.y << 16);
    f[3] = __uint_as_float(u.y & 0xffff0000u);
    f[4] = __uint_as_float(u.z << 16);
    f[5] = __uint_as_float(u.z & 0xffff0000u);
    f[6] = __uint_as_float(u.w << 16);
    f[7] = __uint_as_float(u.w & 0xffff0000u);
}

// ---------------- CSR build ----------------

__global__ __launch_bounds__(256) void k_zero(int* deg) {
    int i = blockIdx.x * 256 + threadIdx.x;
    if (i < N_NODES) deg[i] = 0;
}

__global__ __launch_bounds__(256) void k_deg(const int* edst, int* deg) {
    int e = blockIdx.x * 256 + threadIdx.x;
    if (e < N_EDGES) atomicAdd(&deg[edst[e]], 1);
}

__global__ __launch_bounds__(1024) void k_scan(const int* deg, int* off, int* cursor) {
    __shared__ int sd[1024];
    __shared__ int carry;
    int tid = threadIdx.x;
    if (tid == 0) { off[0] = 0; carry = 0; }
    __syncthreads();
    for (int b0 = 0; b0 < N_NODES; b0 += 1024) {
        int v = (b0 + tid < N_NODES) ? deg[b0 + tid] : 0;
        sd[tid] = v;
        __syncthreads();
        for (int s = 1; s < 1024; s <<= 1) {
            int add = (tid >= s) ? sd[tid - s] : 0;
            __syncthreads();
            sd[tid] += add;
            __syncthreads();
        }
        int incl = sd[tid];
        if (b0 + tid < N_NODES) {
            off[b0 + tid + 1]  = carry + incl;
            cursor[b0 + tid]   = carry + incl - v;
        }
        __syncthreads();
        if (tid == 0) carry += sd[1023];
        __syncthreads();
    }
}

__global__ __launch_bounds__(256) void k_scatter(const int* edst, int* cursor, int* elist) {
    int e = blockIdx.x * 256 + threadIdx.x;
    if (e < N_EDGES) {
        int p = atomicAdd(&cursor[edst[e]], 1);
        elist[p] = e;
    }
}

// gather per-edge data into CSR order; also precompute Yf[E][16] fp32
__global__ __launch_bounds__(256) void k_reorder(const int* elist, const int* esrc, const int* edst,
        const float* dist, const float* swit, const float* vec,
        int* src_c, int* dst_c, float* dist_c, float* sc_c,
        float* vx_c, float* vy_c, float* vz_c, float* Yf) {
    int i = blockIdx.x * 256 + threadIdx.x;
    if (i >= N_EDGES) return;
    int e = elist[i];
    float d = dist[e];
    float inv = 1.0f / d;
    float vx = vec[(size_t)e*3 + 0] * inv;
    float vy = vec[(size_t)e*3 + 1] * inv;
    float vz = vec[(size_t)e*3 + 2] * inv;
    src_c[i]  = esrc[e];
    dst_c[i]  = edst[e];
    dist_c[i] = d;
    sc_c[i]   = swit[e] * 0.25f;           // switch / sqrt(ATT)
    vx_c[i]   = vx;
    vy_c[i]   = vy;
    vz_c[i]   = vz;
    float Y[16];
    sph16(vx, vy, vz, Y);
    #pragma unroll
    for (int m = 0; m < 16; m += 4)
        *(float4*)&Yf[(size_t)i * 16 + m] = make_float4(Y[m], Y[m+1], Y[m+2], Y[m+3]);
}

// ---------------- weight prep (fp32 -> transposed bf16, padded) ----------------

__global__ __launch_bounds__(256) void k_prep_qkv(const float* wq, const float* wk,
                                                  const float* wv, ushort_t* Wtq) {
    int id = blockIdx.x * 256 + threadIdx.x;
    if (id >= 192 * 832) return;
    int k = id / 832, n = id - (id / 832) * 832;
    float v = 0.0f;
    if (k < DIM && n < QKV_W)
        v = (n < 320) ? wq[k * 320 + n] : (n < 640) ? wk[k * 320 + (n - 320)]
                                                    : wv[k * DIM + (n - 640)];
    Wtq[(size_t)n * KQ + k] = f2bf(v);
}

__global__ __launch_bounds__(256) void k_prep_upd(const float* uw, ushort_t* Wtu) {
    int id = blockIdx.x * 256 + threadIdx.x;
    if (id >= 352 * 192) return;
    int k = id / 192, n = id - (id / 192) * 192;
    float v = (n < DIM) ? uw[k * DIM + n] : 0.0f;
    Wtu[(size_t)n * UI_W + k] = f2bf(v);
}

// ---------------- MFMA GEMM ----------------

template<int KCHUNKS, bool BF16OUT>
__global__ __launch_bounds__(256) void k_gemm(const ushort_t* __restrict__ A, int sA,
                                              const ushort_t* __restrict__ Bt, int sB,
                                              void* __restrict__ Cv, int sC, int M, int N) {
    __shared__ ushort_t As[64 * 40];
    __shared__ ushort_t Bs[64 * 40];
    int tid  = threadIdx.x;
    int m0   = blockIdx.y * 64, n0 = blockIdx.x * 64;
    int w    = tid >> 6, lane = tid & 63, quad = lane >> 4, c16 = lane & 15;
    int arow = tid >> 2, aseg = tid & 3;
    f32x4 acc[4] = {};
    for (int kc = 0; kc < KCHUNKS; kc++) {
        int k0 = kc * 32;
        *(uint4*)&As[arow * 40 + aseg * 8] =
            *(const uint4*)&A[(size_t)(m0 + arow) * sA + k0 + aseg * 8];
        *(uint4*)&Bs[arow * 40 + aseg * 8] =
            *(const uint4*)&Bt[(size_t)(n0 + arow) * sB + k0 + aseg * 8];
        __syncthreads();
        bf16x8 a = *(const bf16x8*)&As[(w * 16 + c16) * 40 + quad * 8];
        #pragma unroll
        for (int t = 0; t < 4; t++) {
            bf16x8 b = *(const bf16x8*)&Bs[(t * 16 + c16) * 40 + quad * 8];
            acc[t] = __builtin_amdgcn_mfma_f32_16x16x32_bf16(a, b, acc[t], 0, 0, 0);
        }
        __syncthreads();
    }
    #pragma unroll
    for (int t = 0; t < 4; t++) {
        #pragma unroll
        for (int r = 0; r < 4; r++) {
            int row = m0 + w * 16 + quad * 4 + r;
            int col = n0 + t * 16 + c16;
            if (row < M && col < N) {
                if (BF16OUT)
                    ((ushort_t*)Cv)[(size_t)row * sC + col] = f2bf(acc[t][r]);
                else
                    ((float*)Cv)[(size_t)row * sC + col] = acc[t][r];
            }
        }
    }
}

// ---------------- node embedding ----------------

__global__ __launch_bounds__(256) void k_node_init(const int* species, const float* z_table,
                                                   const float* wsp, float* xi,
                                                   ushort_t* xib, ushort_t* cxm) {
    __shared__ float zs[16 * ZDIM];
    __shared__ float yt[16 * DIM];
    __shared__ float red[256];
    __shared__ float mus[16], rstds[16];
    int base = blockIdx.x * 16;
    int tid  = threadIdx.x;
    { int n = tid >> 4, kk = tid & 15;
      zs[tid] = z_table[species[base + n] * ZDIM + kk]; }
    __syncthreads();
    int c = tid;
    if (c < DIM) {
        float acc[16];
        #pragma unroll
        for (int n = 0; n < 16; n++) acc[n] = 0.0f;
        for (int kk = 0; kk < ZDIM; kk++) {
            float w = wsp[kk * DIM + c];
            #pragma unroll
            for (int n = 0; n < 16; n++) acc[n] += zs[n * ZDIM + kk] * w;
        }
        #pragma unroll
        for (int n = 0; n < 16; n++) yt[n * DIM + c] = acc[n];
    }
    __syncthreads();
    { int n2 = tid >> 4, j = tid & 15;
      float s = 0.0f;
      for (int c2 = j; c2 < DIM; c2 += 16) s += yt[n2 * DIM + c2];
      red[tid] = s; }
    __syncthreads();
    if (tid < 16) { float s = 0; for (int j = 0; j < 16; j++) s += red[tid * 16 + j]; mus[tid] = s / (float)DIM; }
    __syncthreads();
    { int n2 = tid >> 4, j = tid & 15;
      float mu = mus[n2], s = 0.0f;
      for (int c2 = j; c2 < DIM; c2 += 16) { float d = yt[n2 * DIM + c2] - mu; s += d * d; }
      red[tid] = s; }
    __syncthreads();
    if (tid < 16) { float s = 0; for (int j = 0; j < 16; j++) s += red[tid * 16 + j]; rstds[tid] = rsqrtf(s / (float)DIM + 1e-6f); }
    __syncthreads();
    if (c < DIM) {
        #pragma unroll
        for (int n = 0; n < 16; n++) {
            float val = (yt[n * DIM + c] - mus[n]) * rstds[n];
            xi[(size_t)(base + n) * DIM + c] = val;
            ushort_t bv = f2bf(val);
            xib[(size_t)(base + n) * KQ + c]   = bv;
            cxm[(size_t)(base + n) * UI_W + c] = bv;
        }
    } else if (c < KQ) {
        #pragma unroll
        for (int n = 0; n < 16; n++) xib[(size_t)(base + n) * KQ + c] = 0;
    }
}

// ---------------- edge kernel, layer 0 (SoA aij[h][edge]) ----------------

__global__ __launch_bounds__(256) void k_edge0(const int* src_c, const int* dst_c,
        const float* dist_c, const float* sc_c,
        const ushort_t* qkvh,
        const float* pw1, const float* pb1, const float* pw2, const float* pb2,
        float* aij) {
    __shared__ float s_w1[RDIM * 32], s_w2[32 * 16], s_b1[32], s_b2[16];
    int tid = threadIdx.x;
    for (int i = tid; i < RDIM * 32; i += 256) s_w1[i] = pw1[i];
    for (int i = tid; i < 32 * 16; i += 256) s_w2[i] = pw2[i];
    if (tid < 32) s_b1[tid] = pb1[tid];
    if (tid < 16) s_b2[tid] = pb2[tid];
    __syncthreads();
    int i = blockIdx.x * 256 + tid;
    if (i >= N_EDGES) return;
    float d = dist_c[i], sc = sc_c[i];
    int s = src_c[i], t_ = dst_c[i];
    float ur[RDIM];
    #pragma unroll
    for (int r = 0; r < 16; r++) {
        float cc = 0.8f + (float)r * RSTEP;
        float u  = (d - cc) * SIGINV;
        ur[r] = __expf(-u * u);
    }
    float wd[16];
    #pragma unroll
    for (int dd = 0; dd < 16; dd++) wd[dd] = s_b2[dd];
    for (int j = 0; j < 32; j++) {
        float a = s_b1[j];
        #pragma unroll
        for (int r = 0; r < 16; r++) a += ur[r] * s_w1[r * 32 + j];
        float sj = a / (1.0f + __expf(-a));
        #pragma unroll
        for (int dd = 0; dd < 16; dd++) wd[dd] += sj * s_w2[j * 16 + dd];
    }
    const uint4* q4 = (const uint4*)(qkvh + (size_t)t_ * QKV_W);
    const uint4* k4 = (const uint4*)(qkvh + (size_t)s  * QKV_W + QK_W);
    for (int h = 0; h < NH; h++) {
        float qa[8], qb[8], ka[8], kb[8];
        unpack8(q4[2*h],   qa); unpack8(q4[2*h+1], qb);
        unpack8(k4[2*h],   ka); unpack8(k4[2*h+1], kb);
        float acc = 0.0f;
        #pragma unroll
        for (int dd = 0; dd < 8; dd++) acc += qa[dd] * ka[dd] * wd[dd];
        #pragma unroll
        for (int dd = 0; dd < 8; dd++) acc += qb[dd] * kb[dd] * wd[8 + dd];
        aij[(size_t)h * N_EDGES + i] = acc * sc;
    }
}

// ---------------- edge kernel, layer 1 (SoA aij[h][edge]) ----------------

__global__ __launch_bounds__(256) void k_edge1(const int* src_c, const int* dst_c,
        const float* dist_c, const float* sc_c,
        const float* vx_c, const float* vy_c, const float* vz_c,
        const ushort_t* qkvh, const ushort_t* Vih,
        const float* pw1, const float* pb1, const float* pw2, const float* pb2,
        float* aij) {
    __shared__ float s_w1[32 * 32], s_w2[32 * 16], s_b1[32], s_b2[16];
    int tid = threadIdx.x;
    for (int i = tid; i < 32 * 32; i += 256) s_w1[i] = pw1[i];
    for (int i = tid; i < 32 * 16; i += 256) s_w2[i] = pw2[i];
    if (tid < 32) s_b1[tid] = pb1[tid];
    if (tid < 16) s_b2[tid] = pb2[tid];
    __syncthreads();
    int i = blockIdx.x * 256 + tid;
    if (i >= N_EDGES) return;
    float d = dist_c[i], sc = sc_c[i];
    int s = src_c[i], t_ = dst_c[i];
    float ur[32];
    #pragma unroll
    for (int r = 0; r < 16; r++) {
        float cc = 0.8f + (float)r * RSTEP;
        float u  = (d - cc) * SIGINV;
        ur[r] = __expf(-u * u);
    }
    float Y[16];
    sph16(vx_c[i], vy_c[i], vz_c[i], Y);
    const uint4* vd4 = (const uint4*)(Vih + (size_t)t_ * 64);
    const uint4* vs4 = (const uint4*)(Vih + (size_t)s  * 64);
    #pragma unroll
    for (int th = 0; th < THH; th++) {
        float fd[16], fs[16];
        unpack8(vd4[2*th],   fd);     unpack8(vd4[2*th+1], fd+8);
        unpack8(vs4[2*th],   fs);     unpack8(vs4[2*th+1], fs+8);
        float us0 = (fd[0] + fs[0]) * Y[0];
        float us1 = 0.0f, us2 = 0.0f, us3 = 0.0f;
        #pragma unroll
        for (int m = 1; m < 4; m++)  us1 += (fd[m] - fs[m]) * Y[m];
        #pragma unroll
        for (int m = 4; m < 9; m++)  us2 += (fd[m] + fs[m]) * Y[m];
        #pragma unroll
        for (int m = 9; m < 16; m++) us3 += (fd[m] - fs[m]) * Y[m];
        ur[16 + 0 * 4 + th] = us0;
        ur[16 + 1 * 4 + th] = us1;
        ur[16 + 2 * 4 + th] = us2;
        ur[16 + 3 * 4 + th] = us3;
    }
    float wd[16];
    #pragma unroll
    for (int dd = 0; dd < 16; dd++) wd[dd] = s_b2[dd];
    for (int j = 0; j < 32; j++) {
        float a = s_b1[j];
        #pragma unroll
        for (int r = 0; r < 32; r++) a += ur[r] * s_w1[r * 32 + j];
        float sj = a / (1.0f + __expf(-a));
        #pragma unroll
        for (int dd = 0; dd < 16; dd++) wd[dd] += sj * s_w2[j * 16 + dd];
    }
    const uint4* q4 = (const uint4*)(qkvh + (size_t)t_ * QKV_W);
    const uint4* k4 = (const uint4*)(qkvh + (size_t)s  * QKV_W + QK_W);
    for (int h = 0; h < NH; h++) {
        float qa[8], qb[8], ka[8], kb[8];
        unpack8(q4[2*h],   qa); unpack8(q4[2*h+1], qb);
        unpack8(k4[2*h],   ka); unpack8(k4[2*h+1], kb);
        float acc = 0.0f;
        #pragma unroll
        for (int dd = 0; dd < 8; dd++) acc += qa[dd] * ka[dd] * wd[dd];
        #pragma unroll
        for (int dd = 0; dd < 8; dd++) acc += qb[dd] * kb[dd] * wd[8 + dd];
        aij[(size_t)h * N_EDGES + i] = acc * sc;
    }
}

// ---------------- aggregation: one wave per node (mi), 4 nodes/wave (Vi) ----------

// mi accumulation for one node on lanes 0..43 of a wave (4 channels per lane)
__device__ __forceinline__ void mi_wave(int n, int lane, const int* off, const int* src_c,
        const float* aij, const ushort_t* qkvh, ushort_t* cxm) {
    if (lane >= 44) return;
    int c0 = lane * 4;
    int hA = c0 / VD;
    int hB = (c0 + 3) / VD;
    bool f1 = ((c0 + 1) / VD) != hA;
    bool f2 = ((c0 + 2) / VD) != hA;
    const float* aA = aij + (size_t)hA * N_EDGES;
    const float* aB = aij + (size_t)hB * N_EDGES;
    int start = off[n], end = off[n + 1];
    float acc0 = 0, acc1 = 0, acc2 = 0, acc3 = 0;
    int i = start;
    for (; i + 2 <= end; i += 2) {
        int s0 = src_c[i], s1 = src_c[i + 1];
        uint2 v0 = *(const uint2*)(qkvh + (size_t)s0 * QKV_W + 640 + c0);
        uint2 v1 = *(const uint2*)(qkvh + (size_t)s1 * QKV_W + 640 + c0);
        float a00 = aA[i], a0B = aB[i], a10 = aA[i + 1], a1B = aB[i + 1];
        float g01 = f1 ? a0B : a00, g02 = f2 ? a0B : a00;
        float g11 = f1 ? a1B : a10, g12 = f2 ? a1B : a10;
        acc0 += a00 * __uint_as_float(v0.x << 16);
        acc1 += g01 * __uint_as_float(v0.x & 0xffff0000u);
        acc2 += g02 * __uint_as_float(v0.y << 16);
        acc3 += a0B * __uint_as_float(v0.y & 0xffff0000u);
        acc0 += a10 * __uint_as_float(v1.x << 16);
        acc1 += g11 * __uint_as_float(v1.x & 0xffff0000u);
        acc2 += g12 * __uint_as_float(v1.y << 16);
        acc3 += a1B * __uint_as_float(v1.y & 0xffff0000u);
    }
    if (i < end) {
        int s0 = src_c[i];
        uint2 v0 = *(const uint2*)(qkvh + (size_t)s0 * QKV_W + 640 + c0);
        float a00 = aA[i], a0B = aB[i];
        float g01 = f1 ? a0B : a00, g02 = f2 ? a0B : a00;
        acc0 += a00 * __uint_as_float(v0.x << 16);
        acc1 += g01 * __uint_as_float(v0.x & 0xffff0000u);
        acc2 += g02 * __uint_as_float(v0.y << 16);
        acc3 += a0B * __uint_as_float(v0.y & 0xffff0000u);
    }
    ushort_t o[4] = {f2bf(acc0), f2bf(acc1), f2bf(acc2), f2bf(acc3)};
    *(uint2*)(cxm + (size_t)n * UI_W + DIM + c0) = *(uint2*)o;
}

// layer 0: mi waves (10000) + Vi waves (2500, 4 nodes each)
__global__ __launch_bounds__(256) void k_agg0(const int* off, const int* src_c,
        const float* Yf, const float* aij, const ushort_t* qkvh,
        ushort_t* cxm, ushort_t* Vih) {
    int wid  = blockIdx.x * 4 + (threadIdx.x >> 6);
    int lane = threadIdx.x & 63;
    if (wid < N_NODES) {
        mi_wave(wid, lane, off, src_c, aij, qkvh, cxm);
    } else {
        int n = (wid - N_NODES) * 4 + (lane >> 4);
        int u0 = (lane & 15) * 4;
        int th = u0 >> 4, sm0 = u0 & 15;
        const float* ah = aij + (size_t)(SH_HEADS + th) * N_EDGES;
        int start = off[n], end = off[n + 1];
        float acc0 = 0, acc1 = 0, acc2 = 0, acc3 = 0;
        int i = start;
        for (; i + 2 <= end; i += 2) {
            float4 y0 = *(const float4*)(Yf + (size_t)i * 16 + sm0);
            float4 y1 = *(const float4*)(Yf + (size_t)(i + 1) * 16 + sm0);
            float a0 = ah[i], a1 = ah[i + 1];
            acc0 += a0 * y0.x + a1 * y1.x;
            acc1 += a0 * y0.y + a1 * y1.y;
            acc2 += a0 * y0.z + a1 * y1.z;
            acc3 += a0 * y0.w + a1 * y1.w;
        }
        if (i < end) {
            float4 y0 = *(const float4*)(Yf + (size_t)i * 16 + sm0);
            float a0 = ah[i];
            acc0 += a0 * y0.x; acc1 += a0 * y0.y; acc2 += a0 * y0.z; acc3 += a0 * y0.w;
        }
        ushort_t o[4] = {f2bf(acc0), f2bf(acc1), f2bf(acc2), f2bf(acc3)};
        *(uint2*)(Vih + (size_t)n * 64 + u0) = *(uint2*)o;
    }
}

// layer 1: mi only
__global__ __launch_bounds__(256) void k_agg1(const int* off, const int* src_c,
        const float* aij, const ushort_t* qkvh, ushort_t* cxm) {
    int wid  = blockIdx.x * 4 + (threadIdx.x >> 6);
    int lane = threadIdx.x & 63;
    mi_wave(wid, lane, off, src_c, aij, qkvh, cxm);
}

// ---------------- LN epilogue ----------------

__global__ __launch_bounds__(256) void k_lnfinal(const float* yg, const float* xi,
        const float* ub, float* xo, ushort_t* xib, ushort_t* cxm) {
    __shared__ float yt[16 * DIM];
    __shared__ float red[256];
    __shared__ float mus[16], rstds[16];
    int base = blockIdx.x * 16;
    int tid  = threadIdx.x;
    for (int idx = tid; idx < 16 * DIM; idx += 256) {
        int n = idx / DIM, c = idx - n * DIM;
        yt[idx] = xi[(size_t)(base + n) * DIM + c] + yg[(size_t)(base + n) * DIM + c] + ub[c];
    }
    __syncthreads();
    { int n2 = tid >> 4, j = tid & 15;
      float s = 0.0f;
      for (int c2 = j; c2 < DIM; c2 += 16) s += yt[n2 * DIM + c2];
      red[tid] = s; }
    __syncthreads();
    if (tid < 16) { float s = 0; for (int j = 0; j < 16; j++) s += red[tid * 16 + j]; mus[tid] = s / (float)DIM; }
    __syncthreads();
    { int n2 = tid >> 4, j = tid & 15;
      float mu = mus[n2], s = 0.0f;
      for (int c2 = j; c2 < DIM; c2 += 16) { float d = yt[n2 * DIM + c2] - mu; s += d * d; }
      red[tid] = s; }
    __syncthreads();
    if (tid < 16) { float s = 0; for (int j = 0; j < 16; j++) s += red[tid * 16 + j]; rstds[tid] = rsqrtf(s / (float)DIM + 1e-6f); }
    __syncthreads();
    int c = tid;
    if (c < DIM) {
        #pragma unroll
        for (int n = 0; n < 16; n++) {
            float val = (yt[n * DIM + c] - mus[n]) * rstds[n];
            xo[(size_t)(base + n) * DIM + c] = val;
            ushort_t bv = f2bf(val);
            xib[(size_t)(base + n) * KQ + c]   = bv;
            cxm[(size_t)(base + n) * UI_W + c] = bv;
        }
    } else if (c < KQ) {
        #pragma unroll
        for (int n = 0; n < 16; n++) xib[(size_t)(base + n) * KQ + c] = 0;
    }
}

// ---------------- launch ----------------

extern "C" void kernel_launch(void* const* d_in, const int* in_sizes, int n_in,
                              void* d_out, int out_size, void* d_ws, size_t ws_size,
                              hipStream_t stream) {
    const int*   species = (const int*)  d_in[0];
    const float* dist    = (const float*)d_in[1];
    const float* swit    = (const float*)d_in[2];
    const int*   esrc    = (const int*)  d_in[3];
    const int*   edst    = (const int*)  d_in[4];
    const float* vec     = (const float*)d_in[5];
    const float* z_table = (const float*)d_in[6];
    const float* wsp     = (const float*)d_in[7];
    const float* pw1_0 = (const float*)d_in[8],  *pb1_0 = (const float*)d_in[9];
    const float* pw2_0 = (const float*)d_in[10], *pb2_0 = (const float*)d_in[11];
    const float* wq0 = (const float*)d_in[12], *wk0 = (const float*)d_in[13];
    const float* wv0 = (const float*)d_in[14], *uw0 = (const float*)d_in[15];
    const float* ub0 = (const float*)d_in[16];
    const float* pw1_1 = (const float*)d_in[17], *pb1_1 = (const float*)d_in[18];
    const float* pw2_1 = (const float*)d_in[19], *pb2_1 = (const float*)d_in[20];
    const float* wq1 = (const float*)d_in[21], *wk1 = (const float*)d_in[22];
    const float* wv1 = (const float*)d_in[23], *uw1 = (const float*)d_in[24];
    const float* ub1 = (const float*)d_in[25];
    float* out = (float*)d_out;

    char* p = (char*)d_ws;
    auto alloc = [&](size_t bytes) -> char* {
        char* r = p;
        p += (bytes + 255) & ~(size_t)255;
        return r;
    };
    int* deg    = (int*)alloc((size_t)N_NODES * 4);
    int* off    = (int*)alloc((size_t)(N_NODES + 1) * 4);
    int* cursor = (int*)alloc((size_t)N_NODES * 4);
    int* elist  = (int*)alloc((size_t)N_EDGES * 4);
    int*   src_c  = (int*)  alloc((size_t)N_EDGES * 4);
    int*   dst_c  = (int*)  alloc((size_t)N_EDGES * 4);
    float* dist_c = (float*)alloc((size_t)N_EDGES * 4);
    float* sc_c   = (float*)alloc((size_t)N_EDGES * 4);
    float* vx_c   = (float*)alloc((size_t)N_EDGES * 4);
    float* vy_c   = (float*)alloc((size_t)N_EDGES * 4);
    float* vz_c   = (float*)alloc((size_t)N_EDGES * 4);
    float* Yf     = (float*)alloc((size_t)N_EDGES * 16 * 4);
    float* xiA  = (float*)alloc((size_t)N_NODES * DIM * 4);
    float* xiB  = (float*)alloc((size_t)N_NODES * DIM * 4);
    ushort_t* xib  = (ushort_t*)alloc((size_t)N_PAD * KQ * 2);
    ushort_t* cxm  = (ushort_t*)alloc((size_t)N_PAD * UI_W * 2);
    ushort_t* qkvh = (ushort_t*)alloc((size_t)N_NODES * QKV_W * 2);
    float* ybuf    = (float*)alloc((size_t)N_NODES * DIM * 4);
    ushort_t* Wtq0 = (ushort_t*)alloc((size_t)832 * KQ * 2);
    ushort_t* Wtq1 = (ushort_t*)alloc((size_t)832 * KQ * 2);
    ushort_t* Wtu0 = (ushort_t*)alloc((size_t)192 * UI_W * 2);
    ushort_t* Wtu1 = (ushort_t*)alloc((size_t)192 * UI_W * 2);
    ushort_t* Vih  = (ushort_t*)alloc((size_t)N_NODES * 64 * 2);
    float* aij  = (float*)alloc((size_t)N_EDGES * NH * 4);

    const int NB_N  = (N_NODES + 255) / 256;
    const int NB_E  = (N_EDGES + 255) / 256;
    const int NB_T  = N_NODES / 16;   // 625
    const dim3 GRID_QKV(13, 157);
    const dim3 GRID_UPD(3, 157);

    k_zero<<<NB_N, 256, 0, stream>>>(deg);
    k_deg<<<NB_E, 256, 0, stream>>>(edst, deg);
    k_scan<<<1, 1024, 0, stream>>>(deg, off, cursor);
    k_scatter<<<NB_E, 256, 0, stream>>>(edst, cursor, elist);
    k_reorder<<<NB_E, 256, 0, stream>>>(elist, esrc, edst, dist, swit, vec,
                                        src_c, dst_c, dist_c, sc_c, vx_c, vy_c, vz_c, Yf);

    k_prep_qkv<<<624, 256, 0, stream>>>(wq0, wk0, wv0, Wtq0);
    k_prep_qkv<<<624, 256, 0, stream>>>(wq1, wk1, wv1, Wtq1);
    k_prep_upd<<<264, 256, 0, stream>>>(uw0, Wtu0);
    k_prep_upd<<<264, 256, 0, stream>>>(uw1, Wtu1);

    k_node_init<<<NB_T, 256, 0, stream>>>(species, z_table, wsp, xiA, xib, cxm);

    // layer 0
    k_gemm<6, true><<<GRID_QKV, 256, 0, stream>>>(xib, KQ, Wtq0, KQ, qkvh, QKV_W,
                                                  N_NODES, QKV_W);
    k_edge0<<<NB_E, 256, 0, stream>>>(src_c, dst_c, dist_c, sc_c, qkvh,
                                      pw1_0, pb1_0, pw2_0, pb2_0, aij);
    k_agg0<<<3125, 256, 0, stream>>>(off, src_c, Yf, aij, qkvh, cxm, Vih);
    k_gemm<11, false><<<GRID_UPD, 256, 0, stream>>>(cxm, UI_W, Wtu0, UI_W, ybuf, DIM,
                                                    N_NODES, DIM);
    k_lnfinal<<<NB_T, 256, 0, stream>>>(ybuf, xiA, ub0, xiB, xib, cxm);

    // layer 1
    k_gemm<6, true><<<GRID_QKV, 256, 0, stream>>>(xib, KQ, Wtq1, KQ, qkvh, QKV_W,
                                                  N_NODES, QKV_W);
    k_edge1<<<NB_E, 256, 0, stream>>>(src_c, dst_c, dist_c, sc_c, vx_c, vy_c, vz_c,
                                      qkvh, Vih, pw1_1, pb1_1, pw2_1, pb2_1, aij);
    k_agg1<<<2500, 256, 0, stream>>>(off, src_c, aij, qkvh, cxm);
    k_gemm<11, false><<<GRID_UPD, 256, 0, stream>>>(cxm, UI_W, Wtu1, UI_W, ybuf, DIM,
                                                    N_NODES, DIM);
    k_lnfinal<<<NB_T, 256, 0, stream>>>(ybuf, xiB, ub1, out, xib, cxm);
}